// Round 1
// baseline (3816.834 us; speedup 1.0000x reference)
//
#include <hip/hip_runtime.h>
#include <hip/hip_bf16.h>
#include <math.h>

#define BSZ 32
#define SEQ 512
#define DIM 512
#define NH 8
#define DKH 64
#define DFFN 2048
#define NL 2
#define KIDX 5
#define NEGV -1e32f

// ---------------- wave (64-lane) reduce helpers ----------------
__device__ __forceinline__ float wmaxf(float v) {
    #pragma unroll
    for (int m = 32; m > 0; m >>= 1) v = fmaxf(v, __shfl_xor(v, m));
    return v;
}
__device__ __forceinline__ float wsumf(float v) {
    #pragma unroll
    for (int m = 32; m > 0; m >>= 1) v += __shfl_xor(v, m);
    return v;
}
__device__ __forceinline__ int wsumi(int v) {
    #pragma unroll
    for (int m = 32; m > 0; m >>= 1) v += __shfl_xor(v, m);
    return v;
}

// ---------------- x = q + pe, y = qa + pe ----------------
__global__ void add_pe_kernel(const float4* __restrict__ q, const float4* __restrict__ qa,
                              const float4* __restrict__ pe, float4* __restrict__ x,
                              float4* __restrict__ y, int n4) {
    int i = blockIdx.x * 256 + threadIdx.x;
    if (i >= n4) return;
    int pi = i & (SEQ * DIM / 4 - 1);
    float4 p = pe[pi];
    float4 a = q[i], b = qa[i];
    x[i] = make_float4(a.x + p.x, a.y + p.y, a.z + p.z, a.w + p.w);
    y[i] = make_float4(b.x + p.x, b.y + p.y, b.z + p.z, b.w + p.w);
}

// ---------------- C[M,N] = A[M,K] @ B[N,K]^T + bias (optional relu) ----------------
// fp32 vector GEMM. BM=BN=128, BK=16, 256 threads, 8x8 per thread.
template <int RELU>
__global__ __launch_bounds__(256)
void gemm_bt(const float* __restrict__ A, const float* __restrict__ B,
             const float* __restrict__ bias, float* __restrict__ C,
             int M, int N, int K) {
    __shared__ float As[16][132];
    __shared__ float Bs[16][132];
    const int tid = threadIdx.x;
    const int tx = tid & 15, ty = tid >> 4;
    const int m0 = blockIdx.y * 128, n0 = blockIdx.x * 128;
    float acc[8][8] = {};
    for (int k0 = 0; k0 < K; k0 += 16) {
        #pragma unroll
        for (int s = tid; s < 512; s += 256) {
            int r = s >> 2, c4 = s & 3;
            float4 va = *(const float4*)(A + (size_t)(m0 + r) * K + k0 + c4 * 4);
            As[c4 * 4 + 0][r] = va.x; As[c4 * 4 + 1][r] = va.y;
            As[c4 * 4 + 2][r] = va.z; As[c4 * 4 + 3][r] = va.w;
            float4 vb = *(const float4*)(B + (size_t)(n0 + r) * K + k0 + c4 * 4);
            Bs[c4 * 4 + 0][r] = vb.x; Bs[c4 * 4 + 1][r] = vb.y;
            Bs[c4 * 4 + 2][r] = vb.z; Bs[c4 * 4 + 3][r] = vb.w;
        }
        __syncthreads();
        #pragma unroll
        for (int kk = 0; kk < 16; kk++) {
            float a[8], b[8];
            *(float4*)&a[0] = *(const float4*)&As[kk][ty * 8];
            *(float4*)&a[4] = *(const float4*)&As[kk][ty * 8 + 4];
            *(float4*)&b[0] = *(const float4*)&Bs[kk][tx * 8];
            *(float4*)&b[4] = *(const float4*)&Bs[kk][tx * 8 + 4];
            #pragma unroll
            for (int i = 0; i < 8; i++)
                #pragma unroll
                for (int j = 0; j < 8; j++)
                    acc[i][j] = fmaf(a[i], b[j], acc[i][j]);
        }
        __syncthreads();
    }
    float bv[8];
    *(float4*)&bv[0] = *(const float4*)(bias + n0 + tx * 8);
    *(float4*)&bv[4] = *(const float4*)(bias + n0 + tx * 8 + 4);
    #pragma unroll
    for (int i = 0; i < 8; i++) {
        float out[8];
        #pragma unroll
        for (int j = 0; j < 8; j++) {
            float v = acc[i][j] + bv[j];
            if (RELU) v = fmaxf(v, 0.f);
            out[j] = v;
        }
        float* cp = C + (size_t)(m0 + ty * 8 + i) * N + n0 + tx * 8;
        *(float4*)cp = *(float4*)&out[0];
        *(float4*)(cp + 4) = *(float4*)&out[4];
    }
}

// ---------------- scores: s = q_h @ q_h^T / 8, causal(strict-lower) masked ----------------
// grid: (jt=8, it=8, bh=256), block 256. Writes raw masked scores to pbuf.
__global__ __launch_bounds__(256)
void scores_kernel(const float* __restrict__ q, float* __restrict__ pbuf) {
    const int bh = blockIdx.z;
    const int it = blockIdx.y, jt = blockIdx.x;
    const int b = bh >> 3, h = bh & 7;
    const int tid = threadIdx.x, tx = tid & 15, ty = tid >> 4;
    float* prow = pbuf + ((size_t)bh * SEQ + it * 64) * SEQ + jt * 64;
    if (jt > it) {  // fully masked tile
        for (int s = tid; s < 64 * 64; s += 256) {
            int r = s >> 6, c = s & 63;
            prow[(size_t)r * SEQ + c] = NEGV;
        }
        return;
    }
    __shared__ float Qi[DKH][68];  // [d][i]
    __shared__ float Qj[DKH][68];  // [d][j]
    const float* qbase = q + (size_t)b * SEQ * DIM + h * DKH;
    for (int s = tid; s < 64 * 16; s += 256) {
        int r = s >> 4, c4 = s & 15;
        float4 vi = *(const float4*)(qbase + (size_t)(it * 64 + r) * DIM + c4 * 4);
        Qi[c4 * 4 + 0][r] = vi.x; Qi[c4 * 4 + 1][r] = vi.y;
        Qi[c4 * 4 + 2][r] = vi.z; Qi[c4 * 4 + 3][r] = vi.w;
        float4 vj = *(const float4*)(qbase + (size_t)(jt * 64 + r) * DIM + c4 * 4);
        Qj[c4 * 4 + 0][r] = vj.x; Qj[c4 * 4 + 1][r] = vj.y;
        Qj[c4 * 4 + 2][r] = vj.z; Qj[c4 * 4 + 3][r] = vj.w;
    }
    __syncthreads();
    float acc[4][4] = {};
    #pragma unroll
    for (int d = 0; d < DKH; d++) {
        float a[4], bb[4];
        *(float4*)a = *(const float4*)&Qi[d][ty * 4];
        *(float4*)bb = *(const float4*)&Qj[d][tx * 4];
        #pragma unroll
        for (int i = 0; i < 4; i++)
            #pragma unroll
            for (int j = 0; j < 4; j++)
                acc[i][j] = fmaf(a[i], bb[j], acc[i][j]);
    }
    #pragma unroll
    for (int i = 0; i < 4; i++) {
        int gi = it * 64 + ty * 4 + i;
        float out[4];
        #pragma unroll
        for (int j = 0; j < 4; j++) {
            int gj = jt * 64 + tx * 4 + j;
            out[j] = (gj < gi) ? acc[i][j] * 0.125f : NEGV;
        }
        *(float4*)(prow + (size_t)(ty * 4 + i) * SEQ + tx * 4) = *(float4*)out;
    }
}

// ---------------- softmax -> top5 threshold -> second softmax (in place) ----------------
// grid (i=SEQ, bh=256), block 64 (one wave per row).
__global__ __launch_bounds__(64)
void softmax_topk_kernel(float* __restrict__ pbuf) {
    const int i = blockIdx.x;
    const size_t row = (size_t)blockIdx.y * SEQ + i;
    const int lane = threadIdx.x;
    float* p = pbuf + row * SEQ;
    float v[8];
    float4 x0 = *(const float4*)(p + lane * 4);
    float4 x1 = *(const float4*)(p + 256 + lane * 4);
    v[0] = x0.x; v[1] = x0.y; v[2] = x0.z; v[3] = x0.w;
    v[4] = x1.x; v[5] = x1.y; v[6] = x1.z; v[7] = x1.w;
    // first softmax: p = exp(s - max) / sum
    float lm = v[0];
    #pragma unroll
    for (int e = 1; e < 8; e++) lm = fmaxf(lm, v[e]);
    float m1 = wmaxf(lm);
    float ls = 0.f;
    #pragma unroll
    for (int e = 0; e < 8; e++) { v[e] = expf(v[e] - m1); ls += v[e]; }
    float Z = wsumf(ls);
    #pragma unroll
    for (int e = 0; e < 8; e++) v[e] = v[e] / Z;
    // top-5 threshold (5th largest with multiplicity) for rows >= KIDX
    float thr = -INFINITY;
    if (i >= KIDX) {
        int remaining = KIDX;
        float cut = INFINITY;
        #pragma unroll 1
        for (int iter = 0; iter < KIDX; iter++) {
            float l2 = -INFINITY;
            #pragma unroll
            for (int e = 0; e < 8; e++) if (v[e] < cut) l2 = fmaxf(l2, v[e]);
            float m2 = wmaxf(l2);
            int lc = 0;
            #pragma unroll
            for (int e = 0; e < 8; e++) if (v[e] == m2) lc++;
            int c = wsumi(lc);
            if (c >= remaining) { thr = m2; break; }
            remaining -= c; cut = m2;
        }
    }
    // second softmax over kept entries (rows < KIDX keep everything, incl. p==0 slots)
    float lpm = v[0];
    #pragma unroll
    for (int e = 1; e < 8; e++) lpm = fmaxf(lpm, v[e]);
    float pm = wmaxf(lpm);
    float t[8];
    float ls2 = 0.f;
    #pragma unroll
    for (int e = 0; e < 8; e++) {
        bool keep = (i >= KIDX) ? (v[e] >= thr) : true;
        t[e] = keep ? expf(v[e] - pm) : 0.f;
        ls2 += t[e];
    }
    float Z2 = wsumf(ls2);
    #pragma unroll
    for (int e = 0; e < 8; e++) t[e] = t[e] / Z2;
    *(float4*)(p + lane * 4) = make_float4(t[0], t[1], t[2], t[3]);
    *(float4*)(p + 256 + lane * 4) = make_float4(t[4], t[5], t[6], t[7]);
}

// ---------------- out = w @ v per (b,h), row 0 zeroed ----------------
// grid (it=8, bh=256), block 256, 64x64 out tile (full DK), K-loop over j.
__global__ __launch_bounds__(256)
void av_kernel(const float* __restrict__ pbuf, const float* __restrict__ v,
               float* __restrict__ out) {
    const int bh = blockIdx.y, it = blockIdx.x;
    const int b = bh >> 3, h = bh & 7;
    const int tid = threadIdx.x, tx = tid & 15, ty = tid >> 4;
    __shared__ float Ws[64][68];  // [j][i] (transposed w tile)
    __shared__ float Vs[64][68];  // [j][d]
    const float* wbase = pbuf + ((size_t)bh * SEQ + it * 64) * SEQ;
    const float* vbase = v + (size_t)b * SEQ * DIM + h * DKH;
    float acc[4][4] = {};
    for (int j0 = 0; j0 < SEQ; j0 += 64) {
        for (int s = tid; s < 64 * 16; s += 256) {
            int r = s >> 4, c4 = s & 15;
            float4 ww = *(const float4*)(wbase + (size_t)r * SEQ + j0 + c4 * 4);
            Ws[c4 * 4 + 0][r] = ww.x; Ws[c4 * 4 + 1][r] = ww.y;
            Ws[c4 * 4 + 2][r] = ww.z; Ws[c4 * 4 + 3][r] = ww.w;
            float4 vv = *(const float4*)(vbase + (size_t)(j0 + r) * DIM + c4 * 4);
            *(float4*)&Vs[r][c4 * 4] = vv;
        }
        __syncthreads();
        #pragma unroll
        for (int kk = 0; kk < 64; kk++) {
            float a[4], bb[4];
            *(float4*)a = *(const float4*)&Ws[kk][ty * 4];
            *(float4*)bb = *(const float4*)&Vs[kk][tx * 4];
            #pragma unroll
            for (int i = 0; i < 4; i++)
                #pragma unroll
                for (int j = 0; j < 4; j++)
                    acc[i][j] = fmaf(a[i], bb[j], acc[i][j]);
        }
        __syncthreads();
    }
    #pragma unroll
    for (int i = 0; i < 4; i++) {
        int gi = it * 64 + ty * 4 + i;
        float o[4];
        #pragma unroll
        for (int j = 0; j < 4; j++) o[j] = (gi == 0) ? 0.f : acc[i][j];
        *(float4*)(out + ((size_t)b * SEQ + gi) * DIM + h * DKH + tx * 4) = *(float4*)o;
    }
}

// ---------------- dst = LN(x + t) ----------------
// grid 16384, block 64 (one wave per row of 512).
__global__ __launch_bounds__(64)
void add_ln_kernel(const float* __restrict__ x, const float* __restrict__ t,
                   const float* __restrict__ w, const float* __restrict__ b,
                   float* __restrict__ dst) {
    const size_t row = blockIdx.x;
    const int lane = threadIdx.x;
    const float* xr = x + row * DIM;
    const float* tr = t + row * DIM;
    float v[8];
    {
        float4 a0 = *(const float4*)(xr + lane * 4);
        float4 t0 = *(const float4*)(tr + lane * 4);
        float4 a1 = *(const float4*)(xr + 256 + lane * 4);
        float4 t1 = *(const float4*)(tr + 256 + lane * 4);
        v[0] = a0.x + t0.x; v[1] = a0.y + t0.y; v[2] = a0.z + t0.z; v[3] = a0.w + t0.w;
        v[4] = a1.x + t1.x; v[5] = a1.y + t1.y; v[6] = a1.z + t1.z; v[7] = a1.w + t1.w;
    }
    float ls = 0.f;
    #pragma unroll
    for (int e = 0; e < 8; e++) ls += v[e];
    float mean = wsumf(ls) / (float)DIM;
    float ld = 0.f;
    #pragma unroll
    for (int e = 0; e < 8; e++) { float d = v[e] - mean; ld += d * d; }
    float var = wsumf(ld) / (float)DIM;
    float den = sqrtf(var + 1e-5f);
    float wv[8], bv[8];
    *(float4*)&wv[0] = *(const float4*)(w + lane * 4);
    *(float4*)&wv[4] = *(const float4*)(w + 256 + lane * 4);
    *(float4*)&bv[0] = *(const float4*)(b + lane * 4);
    *(float4*)&bv[4] = *(const float4*)(b + 256 + lane * 4);
    float o[8];
    #pragma unroll
    for (int e = 0; e < 8; e++) o[e] = (v[e] - mean) / den * wv[e] + bv[e];
    float* dr = dst + row * DIM;
    *(float4*)(dr + lane * 4) = make_float4(o[0], o[1], o[2], o[3]);
    *(float4*)(dr + 256 + lane * 4) = make_float4(o[4], o[5], o[6], o[7]);
}

extern "C" void kernel_launch(void* const* d_in, const int* in_sizes, int n_in,
                              void* d_out, int out_size, void* d_ws, size_t ws_size,
                              hipStream_t stream) {
    const float* q_embed = (const float*)d_in[0];
    const float* qa_embed = (const float*)d_in[1];
    const float* pe = (const float*)d_in[2];
    const float* Wk = (const float*)d_in[3];
    const float* bk = (const float*)d_in[4];
    const float* Wv = (const float*)d_in[5];
    const float* bv = (const float*)d_in[6];
    const float* Wo = (const float*)d_in[7];
    const float* bo = (const float*)d_in[8];
    const float* W1 = (const float*)d_in[9];
    const float* b1 = (const float*)d_in[10];
    const float* W2 = (const float*)d_in[11];
    const float* b2 = (const float*)d_in[12];
    const float* ln1w = (const float*)d_in[13];
    const float* ln1b = (const float*)d_in[14];
    const float* ln2w = (const float*)d_in[15];
    const float* ln2b = (const float*)d_in[16];

    float* outx = (float*)d_out;
    const size_t NE = (size_t)BSZ * SEQ * DIM;  // 8388608
    float* pbuf = outx + NE;                     // attn region doubles as score scratch

    float* ws = (float*)d_ws;
    float* xbuf = ws;
    float* ybuf = ws + NE;
    float* qbuf = ws + 2 * NE;
    float* vbuf = ws + 3 * NE;
    float* obuf = ws + 4 * NE;
    float* h1buf = ws + 5 * NE;  // 16384 x 2048

    // x = q_embed + pe ; y = qa_embed + pe
    {
        int n4 = (int)(NE / 4);
        add_pe_kernel<<<(n4 + 255) / 256, 256, 0, stream>>>(
            (const float4*)q_embed, (const float4*)qa_embed, (const float4*)pe,
            (float4*)xbuf, (float4*)ybuf, n4);
    }

    const int M = BSZ * SEQ;  // 16384
    for (int l = 0; l < NL; l++) {
        const float* Wk_l = Wk + (size_t)l * DIM * DIM;
        const float* bk_l = bk + (size_t)l * DIM;
        const float* Wv_l = Wv + (size_t)l * DIM * DIM;
        const float* bv_l = bv + (size_t)l * DIM;
        const float* Wo_l = Wo + (size_t)l * DIM * DIM;
        const float* bo_l = bo + (size_t)l * DIM;
        const float* W1_l = W1 + (size_t)l * DFFN * DIM;
        const float* b1_l = b1 + (size_t)l * DFFN;
        const float* W2_l = W2 + (size_t)l * DIM * DFFN;
        const float* b2_l = b2 + (size_t)l * DIM;

        // q = x @ Wk^T + bk   (k == q)
        gemm_bt<0><<<dim3(DIM / 128, M / 128), 256, 0, stream>>>(xbuf, Wk_l, bk_l, qbuf, M, DIM, DIM);
        // v = y @ Wv^T + bv
        gemm_bt<0><<<dim3(DIM / 128, M / 128), 256, 0, stream>>>(ybuf, Wv_l, bv_l, vbuf, M, DIM, DIM);
        // raw masked scores
        scores_kernel<<<dim3(8, 8, BSZ * NH), 256, 0, stream>>>(qbuf, pbuf);
        // softmax + top5 + second softmax (final attn weights in pbuf)
        softmax_topk_kernel<<<dim3(SEQ, BSZ * NH), 64, 0, stream>>>(pbuf);
        // out = w @ v (row 0 zeroed), head-interleaved layout
        av_kernel<<<dim3(8, BSZ * NH), 256, 0, stream>>>(pbuf, vbuf, obuf);
        // proj: tmp(qbuf) = out @ Wo^T + bo
        gemm_bt<0><<<dim3(DIM / 128, M / 128), 256, 0, stream>>>(obuf, Wo_l, bo_l, qbuf, M, DIM, DIM);
        // x = LN(x + tmp)
        add_ln_kernel<<<M, 64, 0, stream>>>(xbuf, qbuf, ln1w + (size_t)l * DIM, ln1b + (size_t)l * DIM, xbuf);
        // h1 = relu(x @ W1^T + b1)
        gemm_bt<1><<<dim3(DFFN / 128, M / 128), 256, 0, stream>>>(xbuf, W1_l, b1_l, h1buf, M, DFFN, DIM);
        // ff(vbuf) = h1 @ W2^T + b2
        gemm_bt<0><<<dim3(DIM / 128, M / 128), 256, 0, stream>>>(h1buf, W2_l, b2_l, vbuf, M, DIM, DFFN);
        // x = LN(x + ff) -> xbuf (or d_out for last layer)
        float* dst = (l == NL - 1) ? outx : xbuf;
        add_ln_kernel<<<M, 64, 0, stream>>>(xbuf, vbuf, ln2w + (size_t)l * DIM, ln2b + (size_t)l * DIM, dst);
    }
}

// Round 4
// 2253.066 us; speedup vs baseline: 1.6941x; 1.6941x over previous
//
#include <hip/hip_runtime.h>
#include <hip/hip_bf16.h>
#include <math.h>

#define BSZ 32
#define SEQ 512
#define DIM 512
#define NH 8
#define DKH 64
#define DFFN 2048
#define NL 2
#define KIDX 5
#define NEGV -1e32f

typedef float f32x4 __attribute__((ext_vector_type(4)));
typedef short bf16x8 __attribute__((ext_vector_type(8)));

// ---------------- wave (64-lane) reduce helpers ----------------
__device__ __forceinline__ float wmaxf(float v) {
    #pragma unroll
    for (int m = 32; m > 0; m >>= 1) v = fmaxf(v, __shfl_xor(v, m));
    return v;
}
__device__ __forceinline__ float wsumf(float v) {
    #pragma unroll
    for (int m = 32; m > 0; m >>= 1) v += __shfl_xor(v, m);
    return v;
}
__device__ __forceinline__ int wsumi(int v) {
    #pragma unroll
    for (int m = 32; m > 0; m >>= 1) v += __shfl_xor(v, m);
    return v;
}

// ---------------- bf16 split helpers ----------------
__device__ __forceinline__ unsigned int bf16_rne(float x) {
    unsigned int u = __float_as_uint(x);
    return (u + 0x7fffu + ((u >> 16) & 1u)) >> 16;
}

__device__ __forceinline__ f32x4 mfma_bf16(bf16x8 a, bf16x8 b, f32x4 c) {
    return __builtin_amdgcn_mfma_f32_16x16x32_bf16(a, b, c, 0, 0, 0);
}

// ---------------- x = q + pe, y = qa + pe ----------------
__global__ void add_pe_kernel(const float4* __restrict__ q, const float4* __restrict__ qa,
                              const float4* __restrict__ pe, float4* __restrict__ x,
                              float4* __restrict__ y, int n4) {
    int i = blockIdx.x * 256 + threadIdx.x;
    if (i >= n4) return;
    int pi = i & (SEQ * DIM / 4 - 1);
    float4 p = pe[pi];
    float4 a = q[i], b = qa[i];
    x[i] = make_float4(a.x + p.x, a.y + p.y, a.z + p.z, a.w + p.w);
    y[i] = make_float4(b.x + p.x, b.y + p.y, b.z + p.z, b.w + p.w);
}

// ---------------- fp32 vector GEMM (round-1 exact arithmetic) ----------------
// C[M,N] = A[M,K] @ B[N,K]^T + bias. BM=BN=128, BK=16, 256 threads, 8x8/thread.
template <int RELU>
__global__ __launch_bounds__(256)
void gemm_bt(const float* __restrict__ A, const float* __restrict__ B,
             const float* __restrict__ bias, float* __restrict__ C,
             int M, int N, int K) {
    __shared__ float As[16][132];
    __shared__ float Bs[16][132];
    const int tid = threadIdx.x;
    const int tx = tid & 15, ty = tid >> 4;
    const int m0 = blockIdx.y * 128, n0 = blockIdx.x * 128;
    float acc[8][8] = {};
    for (int k0 = 0; k0 < K; k0 += 16) {
        #pragma unroll
        for (int s = tid; s < 512; s += 256) {
            int r = s >> 2, c4 = s & 3;
            float4 va = *(const float4*)(A + (size_t)(m0 + r) * K + k0 + c4 * 4);
            As[c4 * 4 + 0][r] = va.x; As[c4 * 4 + 1][r] = va.y;
            As[c4 * 4 + 2][r] = va.z; As[c4 * 4 + 3][r] = va.w;
            float4 vb = *(const float4*)(B + (size_t)(n0 + r) * K + k0 + c4 * 4);
            Bs[c4 * 4 + 0][r] = vb.x; Bs[c4 * 4 + 1][r] = vb.y;
            Bs[c4 * 4 + 2][r] = vb.z; Bs[c4 * 4 + 3][r] = vb.w;
        }
        __syncthreads();
        #pragma unroll
        for (int kk = 0; kk < 16; kk++) {
            float a[8], b[8];
            *(float4*)&a[0] = *(const float4*)&As[kk][ty * 8];
            *(float4*)&a[4] = *(const float4*)&As[kk][ty * 8 + 4];
            *(float4*)&b[0] = *(const float4*)&Bs[kk][tx * 8];
            *(float4*)&b[4] = *(const float4*)&Bs[kk][tx * 8 + 4];
            #pragma unroll
            for (int i = 0; i < 8; i++)
                #pragma unroll
                for (int j = 0; j < 8; j++)
                    acc[i][j] = fmaf(a[i], b[j], acc[i][j]);
        }
        __syncthreads();
    }
    float bv[8];
    *(float4*)&bv[0] = *(const float4*)(bias + n0 + tx * 8);
    *(float4*)&bv[4] = *(const float4*)(bias + n0 + tx * 8 + 4);
    #pragma unroll
    for (int i = 0; i < 8; i++) {
        float out[8];
        #pragma unroll
        for (int j = 0; j < 8; j++) {
            float v = acc[i][j] + bv[j];
            if (RELU) v = fmaxf(v, 0.f);
            out[j] = v;
        }
        float* cp = C + (size_t)(m0 + ty * 8 + i) * N + n0 + tx * 8;
        *(float4*)cp = *(float4*)&out[0];
        *(float4*)(cp + 4) = *(float4*)&out[4];
    }
}

// ---------------- fp32 scores: s = q_h @ q_h^T /8, strict-lower causal ----------------
// 128x128 tile per block, triangular grid (10, BSZ*NH). Bit-identical per-element
// accumulation to round-1 (sequential d=0..63 fmaf chain).
__global__ __launch_bounds__(256)
void scores128_kernel(const float* __restrict__ q, float* __restrict__ pbuf) {
    const int bh = blockIdx.y, b = bh >> 3, h = bh & 7;
    const int x = blockIdx.x;
    const int it = (x >= 6) ? 3 : (x >= 3) ? 2 : (x >= 1) ? 1 : 0;
    const int jt = x - it * (it + 1) / 2;
    const int m0 = it * 128, n0 = jt * 128;
    __shared__ float Qi[64][132];  // [d][row]
    __shared__ float Qj[64][132];
    const float* qbase = q + (size_t)b * SEQ * DIM + h * DKH;
    const int tid = threadIdx.x;
    for (int s = tid; s < 2048; s += 256) {
        int row = (s & 15) | ((s >> 8) << 4);   // bank-friendly: 16 distinct rows/wave
        int c4 = (s >> 4) & 15;
        float4 vi = *(const float4*)(qbase + (size_t)(m0 + row) * DIM + c4 * 4);
        Qi[c4 * 4 + 0][row] = vi.x; Qi[c4 * 4 + 1][row] = vi.y;
        Qi[c4 * 4 + 2][row] = vi.z; Qi[c4 * 4 + 3][row] = vi.w;
        float4 vj = *(const float4*)(qbase + (size_t)(n0 + row) * DIM + c4 * 4);
        Qj[c4 * 4 + 0][row] = vj.x; Qj[c4 * 4 + 1][row] = vj.y;
        Qj[c4 * 4 + 2][row] = vj.z; Qj[c4 * 4 + 3][row] = vj.w;
    }
    __syncthreads();
    const int tx = tid & 15, ty = tid >> 4;
    float acc[8][8] = {};
    #pragma unroll 4
    for (int d = 0; d < 64; d++) {
        float a[8], bb[8];
        *(float4*)&a[0] = *(const float4*)&Qi[d][ty * 8];
        *(float4*)&a[4] = *(const float4*)&Qi[d][ty * 8 + 4];
        *(float4*)&bb[0] = *(const float4*)&Qj[d][tx * 8];
        *(float4*)&bb[4] = *(const float4*)&Qj[d][tx * 8 + 4];
        #pragma unroll
        for (int i = 0; i < 8; i++)
            #pragma unroll
            for (int j = 0; j < 8; j++)
                acc[i][j] = fmaf(a[i], bb[j], acc[i][j]);
    }
    float* prow = pbuf + ((size_t)bh * SEQ + m0) * SEQ + n0;
    #pragma unroll
    for (int i = 0; i < 8; i++) {
        int gi = m0 + ty * 8 + i;
        #pragma unroll
        for (int jq = 0; jq < 2; jq++) {
            float o[4];
            #pragma unroll
            for (int j = 0; j < 4; j++) {
                int gj = n0 + tx * 8 + jq * 4 + j;
                o[j] = (gj < gi) ? acc[i][jq * 4 + j] * 0.125f : NEGV;
            }
            *(float4*)(prow + (size_t)(ty * 8 + i) * SEQ + tx * 8 + jq * 4) = *(float4*)o;
        }
    }
}

// ---------------- unified split-6 bf16-MFMA matmul ----------------
// C[M,N] = A[M,K] @ B[N,K]^T  with ~fp32 fidelity (hi/mid/lo bf16 split, 6 products).
// MODE 0: C = A@B^T + bias          MODE 1: + relu
// MODE 3: av per (b,h): C = W@Vt^T, row0 zeroed, head-interleaved (grid: (4, BSZ*NH))
template <int MODE, int TN>
__global__ __launch_bounds__(256) void mm6(const float* __restrict__ Aall,
                                           const float* __restrict__ Ball,
                                           float* __restrict__ Call,
                                           const float* __restrict__ bias,
                                           int lda, int ldb, int ldc, int K) {
    constexpr int BFR = TN / 16;
    constexpr int MFR = (TN == 128) ? 4 : 2;
    constexpr int BBASE = 3 * 8 * 64;
    __shared__ uint4 lds[3 * 8 * 64 + 3 * BFR * 64];

    const int tid = threadIdx.x, lane = tid & 63, wid = tid >> 6;
    const int wm = (TN == 128) ? (wid >> 1) : wid;
    const int wn = (TN == 128) ? (wid & 1) : 0;

    const float* A;
    const float* B;
    float* C;
    int m0, n0, kmax;
    if constexpr (MODE <= 1) {
        m0 = blockIdx.y * 128;
        n0 = blockIdx.x * 128;
        A = Aall; B = Ball; C = Call;
        kmax = K;
    } else {
        const int bh = blockIdx.y, b = bh >> 3, h = bh & 7, rb = blockIdx.x;
        m0 = rb * 128; n0 = 0;
        A = Aall + (size_t)bh * SEQ * SEQ;       // attention weights
        B = Ball + (size_t)bh * DKH * SEQ;       // V transposed [d][j]
        C = Call + ((size_t)b * SEQ) * DIM + h * DKH;
        kmax = rb ? (rb + 1) * 128 : SEQ;        // rows 0..4 need full K
    }

    f32x4 acc[MFR][4] = {};

    for (int k0 = 0; k0 < kmax; k0 += 32) {
        for (int c = tid; c < (8 + BFR) * 64; c += 256) {
            int fi = c >> 6, lc = c & 63;
            const float* src = (fi < 8)
                ? A + (size_t)(m0 + fi * 16 + (lc & 15)) * lda + k0 + (lc >> 4) * 8
                : B + (size_t)(n0 + (fi - 8) * 16 + (lc & 15)) * ldb + k0 + (lc >> 4) * 8;
            float4 x0 = *(const float4*)src;
            float4 x1 = *(const float4*)(src + 4);
            float xs[8] = {x0.x, x0.y, x0.z, x0.w, x1.x, x1.y, x1.z, x1.w};
            unsigned int hh[8], hm[8], hl[8];
            #pragma unroll
            for (int e = 0; e < 8; e++) {
                float xv = xs[e];
                unsigned int h0 = bf16_rne(xv);
                float r1 = xv - __uint_as_float(h0 << 16);
                unsigned int h1 = bf16_rne(r1);
                float r2 = r1 - __uint_as_float(h1 << 16);
                unsigned int h2 = bf16_rne(r2);
                hh[e] = h0; hm[e] = h1; hl[e] = h2;
            }
            int base = (fi < 8) ? fi * 64 + lc : BBASE + (fi - 8) * 64 + lc;
            int fstride = (fi < 8) ? 8 * 64 : BFR * 64;
            lds[base + 0 * fstride] = make_uint4(hh[0] | (hh[1] << 16), hh[2] | (hh[3] << 16),
                                                 hh[4] | (hh[5] << 16), hh[6] | (hh[7] << 16));
            lds[base + 1 * fstride] = make_uint4(hm[0] | (hm[1] << 16), hm[2] | (hm[3] << 16),
                                                 hm[4] | (hm[5] << 16), hm[6] | (hm[7] << 16));
            lds[base + 2 * fstride] = make_uint4(hl[0] | (hl[1] << 16), hl[2] | (hl[3] << 16),
                                                 hl[4] | (hl[5] << 16), hl[6] | (hl[7] << 16));
        }
        __syncthreads();

        const bf16x8* ldsb = (const bf16x8*)lds;
        bf16x8 afr[MFR][3];
        #pragma unroll
        for (int fm = 0; fm < MFR; fm++)
            #pragma unroll
            for (int p = 0; p < 3; p++)
                afr[fm][p] = ldsb[p * 512 + (wm * MFR + fm) * 64 + lane];
        #pragma unroll
        for (int fn = 0; fn < 4; fn++) {
            bf16x8 b0 = ldsb[BBASE + 0 * (BFR * 64) + (wn * 4 + fn) * 64 + lane];
            bf16x8 b1 = ldsb[BBASE + 1 * (BFR * 64) + (wn * 4 + fn) * 64 + lane];
            bf16x8 b2 = ldsb[BBASE + 2 * (BFR * 64) + (wn * 4 + fn) * 64 + lane];
            #pragma unroll
            for (int fm = 0; fm < MFR; fm++) {
                f32x4 t = acc[fm][fn];
                t = mfma_bf16(afr[fm][0], b0, t);
                t = mfma_bf16(afr[fm][1], b0, t);
                t = mfma_bf16(afr[fm][2], b0, t);
                t = mfma_bf16(afr[fm][0], b1, t);
                t = mfma_bf16(afr[fm][1], b1, t);
                t = mfma_bf16(afr[fm][0], b2, t);
                acc[fm][fn] = t;
            }
        }
        __syncthreads();
    }

    #pragma unroll
    for (int fm = 0; fm < MFR; fm++) {
        int row0 = m0 + (wm * MFR + fm) * 16 + (lane >> 4) * 4;
        #pragma unroll
        for (int fn = 0; fn < 4; fn++) {
            int col = n0 + (wn * 4 + fn) * 16 + (lane & 15);
            float bv = 0.f;
            if constexpr (MODE <= 1) bv = bias[col];
            f32x4 a = acc[fm][fn];
            #pragma unroll
            for (int r = 0; r < 4; r++) {
                int row = row0 + r;
                float val;
                if constexpr (MODE == 0) val = a[r] + bv;
                else if constexpr (MODE == 1) val = fmaxf(a[r] + bv, 0.f);
                else val = (row == 0) ? 0.f : a[r];
                C[(size_t)row * ldc + col] = val;
            }
        }
    }
}

// ---------------- V transpose: vt[b,h][d][j] = v[b][j][h*64+d] ----------------
__global__ __launch_bounds__(256) void transpose_v_kernel(const float* __restrict__ v,
                                                          float* __restrict__ vt) {
    const int bh = blockIdx.y, jt = blockIdx.x;
    const int b = bh >> 3, h = bh & 7;
    __shared__ float L[64][65];
    const int tid = threadIdx.x;
    for (int s = tid; s < 1024; s += 256) {
        int jj = s >> 4, d4 = s & 15;
        float4 x = *(const float4*)(v + ((size_t)(b * SEQ) + jt * 64 + jj) * DIM + h * DKH + d4 * 4);
        L[jj][d4 * 4 + 0] = x.x; L[jj][d4 * 4 + 1] = x.y;
        L[jj][d4 * 4 + 2] = x.z; L[jj][d4 * 4 + 3] = x.w;
    }
    __syncthreads();
    int d = tid >> 2, jq = tid & 3;
    float* dst = vt + ((size_t)bh * DKH + d) * SEQ + jt * 64 + jq * 16;
    #pragma unroll
    for (int c4 = 0; c4 < 4; c4++) {
        float4 o = make_float4(L[jq * 16 + c4 * 4 + 0][d], L[jq * 16 + c4 * 4 + 1][d],
                               L[jq * 16 + c4 * 4 + 2][d], L[jq * 16 + c4 * 4 + 3][d]);
        *(float4*)(dst + c4 * 4) = o;
    }
}

// ---------------- softmax -> top5 threshold -> second softmax (in place) ----------------
__global__ __launch_bounds__(64)
void softmax_topk_kernel(float* __restrict__ pbuf) {
    const int i = blockIdx.x;
    const size_t row = (size_t)blockIdx.y * SEQ + i;
    const int lane = threadIdx.x;
    float* p = pbuf + row * SEQ;
    float v[8];
    {
        int j0 = lane * 4;
        if (j0 < i) {
            float4 x0 = *(const float4*)(p + j0);
            v[0] = (j0 + 0 < i) ? x0.x : NEGV;
            v[1] = (j0 + 1 < i) ? x0.y : NEGV;
            v[2] = (j0 + 2 < i) ? x0.z : NEGV;
            v[3] = (j0 + 3 < i) ? x0.w : NEGV;
        } else { v[0] = v[1] = v[2] = v[3] = NEGV; }
        int j1 = 256 + j0;
        if (j1 < i) {
            float4 x1 = *(const float4*)(p + j1);
            v[4] = (j1 + 0 < i) ? x1.x : NEGV;
            v[5] = (j1 + 1 < i) ? x1.y : NEGV;
            v[6] = (j1 + 2 < i) ? x1.z : NEGV;
            v[7] = (j1 + 3 < i) ? x1.w : NEGV;
        } else { v[4] = v[5] = v[6] = v[7] = NEGV; }
    }
    float lm = v[0];
    #pragma unroll
    for (int e = 1; e < 8; e++) lm = fmaxf(lm, v[e]);
    float m1 = wmaxf(lm);
    float ls = 0.f;
    #pragma unroll
    for (int e = 0; e < 8; e++) { v[e] = expf(v[e] - m1); ls += v[e]; }
    float Z = wsumf(ls);
    #pragma unroll
    for (int e = 0; e < 8; e++) v[e] = v[e] / Z;
    float thr = -INFINITY;
    if (i >= KIDX) {
        int remaining = KIDX;
        float cut = INFINITY;
        #pragma unroll 1
        for (int iter = 0; iter < KIDX; iter++) {
            float l2 = -INFINITY;
            #pragma unroll
            for (int e = 0; e < 8; e++) if (v[e] < cut) l2 = fmaxf(l2, v[e]);
            float m2 = wmaxf(l2);
            int lc = 0;
            #pragma unroll
            for (int e = 0; e < 8; e++) if (v[e] == m2) lc++;
            int c = wsumi(lc);
            if (c >= remaining) { thr = m2; break; }
            remaining -= c; cut = m2;
        }
    }
    float lpm = v[0];
    #pragma unroll
    for (int e = 1; e < 8; e++) lpm = fmaxf(lpm, v[e]);
    float pm = wmaxf(lpm);
    float t[8];
    float ls2 = 0.f;
    #pragma unroll
    for (int e = 0; e < 8; e++) {
        bool keep = (i >= KIDX) ? (v[e] >= thr) : true;
        t[e] = keep ? expf(v[e] - pm) : 0.f;
        ls2 += t[e];
    }
    float Z2 = wsumf(ls2);
    #pragma unroll
    for (int e = 0; e < 8; e++) t[e] = t[e] / Z2;
    *(float4*)(p + lane * 4) = make_float4(t[0], t[1], t[2], t[3]);
    *(float4*)(p + 256 + lane * 4) = make_float4(t[4], t[5], t[6], t[7]);
}

// ---------------- dst = LN(x + t) ----------------
__global__ __launch_bounds__(64)
void add_ln_kernel(const float* __restrict__ x, const float* __restrict__ t,
                   const float* __restrict__ w, const float* __restrict__ b,
                   float* __restrict__ dst) {
    const size_t row = blockIdx.x;
    const int lane = threadIdx.x;
    const float* xr = x + row * DIM;
    const float* tr = t + row * DIM;
    float v[8];
    {
        float4 a0 = *(const float4*)(xr + lane * 4);
        float4 t0 = *(const float4*)(tr + lane * 4);
        float4 a1 = *(const float4*)(xr + 256 + lane * 4);
        float4 t1 = *(const float4*)(tr + 256 + lane * 4);
        v[0] = a0.x + t0.x; v[1] = a0.y + t0.y; v[2] = a0.z + t0.z; v[3] = a0.w + t0.w;
        v[4] = a1.x + t1.x; v[5] = a1.y + t1.y; v[6] = a1.z + t1.z; v[7] = a1.w + t1.w;
    }
    float ls = 0.f;
    #pragma unroll
    for (int e = 0; e < 8; e++) ls += v[e];
    float mean = wsumf(ls) / (float)DIM;
    float ld = 0.f;
    #pragma unroll
    for (int e = 0; e < 8; e++) { float d = v[e] - mean; ld += d * d; }
    float var = wsumf(ld) / (float)DIM;
    float den = sqrtf(var + 1e-5f);
    float wv[8], bv[8];
    *(float4*)&wv[0] = *(const float4*)(w + lane * 4);
    *(float4*)&wv[4] = *(const float4*)(w + 256 + lane * 4);
    *(float4*)&bv[0] = *(const float4*)(b + lane * 4);
    *(float4*)&bv[4] = *(const float4*)(b + 256 + lane * 4);
    float o[8];
    #pragma unroll
    for (int e = 0; e < 8; e++) o[e] = (v[e] - mean) / den * wv[e] + bv[e];
    float* dr = dst + row * DIM;
    *(float4*)(dr + lane * 4) = make_float4(o[0], o[1], o[2], o[3]);
    *(float4*)(dr + 256 + lane * 4) = make_float4(o[4], o[5], o[6], o[7]);
}

extern "C" void kernel_launch(void* const* d_in, const int* in_sizes, int n_in,
                              void* d_out, int out_size, void* d_ws, size_t ws_size,
                              hipStream_t stream) {
    const float* q_embed = (const float*)d_in[0];
    const float* qa_embed = (const float*)d_in[1];
    const float* pe = (const float*)d_in[2];
    const float* Wk = (const float*)d_in[3];
    const float* bk = (const float*)d_in[4];
    const float* Wv = (const float*)d_in[5];
    const float* bv = (const float*)d_in[6];
    const float* Wo = (const float*)d_in[7];
    const float* bo = (const float*)d_in[8];
    const float* W1 = (const float*)d_in[9];
    const float* b1 = (const float*)d_in[10];
    const float* W2 = (const float*)d_in[11];
    const float* b2 = (const float*)d_in[12];
    const float* ln1w = (const float*)d_in[13];
    const float* ln1b = (const float*)d_in[14];
    const float* ln2w = (const float*)d_in[15];
    const float* ln2b = (const float*)d_in[16];

    float* outx = (float*)d_out;
    const size_t NE = (size_t)BSZ * SEQ * DIM;   // 8388608
    float* pbuf = outx + NE;                     // attn weights region = scores scratch

    float* ws = (float*)d_ws;
    float* xbuf = ws;
    float* ybuf = ws + NE;
    float* qbuf = ws + 2 * NE;
    float* vbuf = ws + 3 * NE;
    float* obuf = ws + 4 * NE;
    float* vtbuf = ws + 5 * NE;   // overlaps h1 region (dead before FF1 writes h1)
    float* h1buf = ws + 5 * NE;   // 16384 x 2048

    {
        int n4 = (int)(NE / 4);
        add_pe_kernel<<<(n4 + 255) / 256, 256, 0, stream>>>(
            (const float4*)q_embed, (const float4*)qa_embed, (const float4*)pe,
            (float4*)xbuf, (float4*)ybuf, n4);
    }

    const int M = BSZ * SEQ;  // 16384
    for (int l = 0; l < NL; l++) {
        const float* Wk_l = Wk + (size_t)l * DIM * DIM;
        const float* bk_l = bk + (size_t)l * DIM;
        const float* Wv_l = Wv + (size_t)l * DIM * DIM;
        const float* bv_l = bv + (size_t)l * DIM;
        const float* Wo_l = Wo + (size_t)l * DIM * DIM;
        const float* bo_l = bo + (size_t)l * DIM;
        const float* W1_l = W1 + (size_t)l * DFFN * DIM;
        const float* b1_l = b1 + (size_t)l * DFFN;
        const float* W2_l = W2 + (size_t)l * DIM * DFFN;
        const float* b2_l = b2 + (size_t)l * DIM;

        // q = x @ Wk^T + bk  (fp32 VALU — selection-critical, round-1 arithmetic)
        gemm_bt<0><<<dim3(DIM / 128, M / 128), 256, 0, stream>>>(
            xbuf, Wk_l, bk_l, qbuf, M, DIM, DIM);
        // v = y @ Wv^T + bv  (MFMA split-6)
        mm6<0, 128><<<dim3(DIM / 128, M / 128), 256, 0, stream>>>(
            ybuf, Wv_l, vbuf, bv_l, DIM, DIM, DIM, DIM);
        // vt[b,h][d][j]
        transpose_v_kernel<<<dim3(8, BSZ * NH), 256, 0, stream>>>(vbuf, vtbuf);
        // scores (fp32 VALU — selection-critical, round-1 arithmetic)
        scores128_kernel<<<dim3(10, BSZ * NH), 256, 0, stream>>>(qbuf, pbuf);
        // softmax + top5 + second softmax (final attn weights in pbuf)
        softmax_topk_kernel<<<dim3(SEQ, BSZ * NH), 64, 0, stream>>>(pbuf);
        // out = W @ V (row 0 zeroed), head-interleaved (MFMA split-6)
        mm6<3, 64><<<dim3(4, BSZ * NH), 256, 0, stream>>>(
            pbuf, vtbuf, obuf, nullptr, SEQ, SEQ, DIM, SEQ);
        // proj: qbuf = out @ Wo^T + bo
        mm6<0, 128><<<dim3(DIM / 128, M / 128), 256, 0, stream>>>(
            obuf, Wo_l, qbuf, bo_l, DIM, DIM, DIM, DIM);
        // x = LN(x + proj)
        add_ln_kernel<<<M, 64, 0, stream>>>(xbuf, qbuf, ln1w + (size_t)l * DIM,
                                            ln1b + (size_t)l * DIM, xbuf);
        // h1 = relu(x @ W1^T + b1)
        mm6<1, 128><<<dim3(DFFN / 128, M / 128), 256, 0, stream>>>(
            xbuf, W1_l, h1buf, b1_l, DIM, DIM, DFFN, DIM);
        // ff = h1 @ W2^T + b2
        mm6<0, 128><<<dim3(DIM / 128, M / 128), 256, 0, stream>>>(
            h1buf, W2_l, vbuf, b2_l, DFFN, DFFN, DIM, DFFN);
        // x = LN(x + ff)
        float* dst = (l == NL - 1) ? outx : xbuf;
        add_ln_kernel<<<M, 64, 0, stream>>>(xbuf, vbuf, ln2w + (size_t)l * DIM,
                                            ln2b + (size_t)l * DIM, dst);
    }
}

// Round 5
// 2193.542 us; speedup vs baseline: 1.7400x; 1.0271x over previous
//
#include <hip/hip_runtime.h>
#include <hip/hip_bf16.h>
#include <math.h>

#define BSZ 32
#define SEQ 512
#define DIM 512
#define NH 8
#define DKH 64
#define DFFN 2048
#define NL 2
#define KIDX 5
#define NEGV -1e32f

typedef float f32x4 __attribute__((ext_vector_type(4)));
typedef short bf16x8 __attribute__((ext_vector_type(8)));
typedef unsigned short ushort_t;

// ---------------- wave (64-lane) reduce helpers ----------------
__device__ __forceinline__ float wmaxf(float v) {
    #pragma unroll
    for (int m = 32; m > 0; m >>= 1) v = fmaxf(v, __shfl_xor(v, m));
    return v;
}
__device__ __forceinline__ float wsumf(float v) {
    #pragma unroll
    for (int m = 32; m > 0; m >>= 1) v += __shfl_xor(v, m);
    return v;
}
__device__ __forceinline__ int wsumi(int v) {
    #pragma unroll
    for (int m = 32; m > 0; m >>= 1) v += __shfl_xor(v, m);
    return v;
}

// ---------------- bf16 split helpers ----------------
__device__ __forceinline__ unsigned int bf16_rne(float x) {
    unsigned int u = __float_as_uint(x);
    return (u + 0x7fffu + ((u >> 16) & 1u)) >> 16;
}
__device__ __forceinline__ void split3_8(const float* xs, unsigned int* hh,
                                         unsigned int* hm, unsigned int* hl) {
    #pragma unroll
    for (int e = 0; e < 8; e++) {
        float x = xs[e];
        unsigned int h0 = bf16_rne(x);
        float r1 = x - __uint_as_float(h0 << 16);
        unsigned int h1 = bf16_rne(r1);
        float r2 = r1 - __uint_as_float(h1 << 16);
        hh[e] = h0; hm[e] = h1; hl[e] = bf16_rne(r2);
    }
}
__device__ __forceinline__ uint4 pack8(const unsigned int* h) {
    return make_uint4(h[0] | (h[1] << 16), h[2] | (h[3] << 16),
                      h[4] | (h[5] << 16), h[6] | (h[7] << 16));
}

__device__ __forceinline__ f32x4 mfma_bf16(bf16x8 a, bf16x8 b, f32x4 c) {
    return __builtin_amdgcn_mfma_f32_16x16x32_bf16(a, b, c, 0, 0, 0);
}

// ---------------- add_pe: old (x,y fp32) and new (x fp32 + y planes) ----------------
__global__ void add_pe_old(const float4* __restrict__ q, const float4* __restrict__ qa,
                           const float4* __restrict__ pe, float4* __restrict__ x,
                           float4* __restrict__ y, int n4) {
    int i = blockIdx.x * 256 + threadIdx.x;
    if (i >= n4) return;
    int pi = i & (SEQ * DIM / 4 - 1);
    float4 p = pe[pi];
    float4 a = q[i], b = qa[i];
    x[i] = make_float4(a.x + p.x, a.y + p.y, a.z + p.z, a.w + p.w);
    y[i] = make_float4(b.x + p.x, b.y + p.y, b.z + p.z, b.w + p.w);
}

__global__ void add_pe_new(const float* __restrict__ q, const float* __restrict__ qa,
                           const float* __restrict__ pe, float* __restrict__ x,
                           ushort_t* __restrict__ ypl, size_t yelems, int n8) {
    int i = blockIdx.x * 256 + threadIdx.x;
    if (i >= n8) return;
    size_t base = (size_t)i * 8;
    size_t pb = base & (size_t)(SEQ * DIM - 1);
    float4 a0 = *(const float4*)(q + base), a1 = *(const float4*)(q + base + 4);
    float4 b0 = *(const float4*)(qa + base), b1 = *(const float4*)(qa + base + 4);
    float4 p0 = *(const float4*)(pe + pb), p1 = *(const float4*)(pe + pb + 4);
    float4 x0 = make_float4(a0.x + p0.x, a0.y + p0.y, a0.z + p0.z, a0.w + p0.w);
    float4 x1 = make_float4(a1.x + p1.x, a1.y + p1.y, a1.z + p1.z, a1.w + p1.w);
    *(float4*)(x + base) = x0;
    *(float4*)(x + base + 4) = x1;
    float ys[8] = {b0.x + p0.x, b0.y + p0.y, b0.z + p0.z, b0.w + p0.w,
                   b1.x + p1.x, b1.y + p1.y, b1.z + p1.z, b1.w + p1.w};
    unsigned int hh[8], hm[8], hl[8];
    split3_8(ys, hh, hm, hl);
    *(uint4*)(ypl + base) = pack8(hh);
    *(uint4*)(ypl + yelems + base) = pack8(hm);
    *(uint4*)(ypl + 2 * yelems + base) = pack8(hl);
}

// ---------------- weight pre-split: fp32 -> 3 bf16 planes ----------------
__global__ void split3w(const float* __restrict__ W, ushort_t* __restrict__ out,
                        size_t elems, int n8) {
    int i = blockIdx.x * 256 + threadIdx.x;
    if (i >= n8) return;
    size_t base = (size_t)i * 8;
    float4 a0 = *(const float4*)(W + base), a1 = *(const float4*)(W + base + 4);
    float xs[8] = {a0.x, a0.y, a0.z, a0.w, a1.x, a1.y, a1.z, a1.w};
    unsigned int hh[8], hm[8], hl[8];
    split3_8(xs, hh, hm, hl);
    *(uint4*)(out + base) = pack8(hh);
    *(uint4*)(out + elems + base) = pack8(hm);
    *(uint4*)(out + 2 * elems + base) = pack8(hl);
}

// ---------------- fp32 vector GEMM (round-1 exact arithmetic, selection-critical) ----------------
template <int RELU>
__global__ __launch_bounds__(256)
void gemm_bt(const float* __restrict__ A, const float* __restrict__ B,
             const float* __restrict__ bias, float* __restrict__ C,
             int M, int N, int K) {
    __shared__ float As[16][132];
    __shared__ float Bs[16][132];
    const int tid = threadIdx.x;
    const int tx = tid & 15, ty = tid >> 4;
    const int m0 = blockIdx.y * 128, n0 = blockIdx.x * 128;
    float acc[8][8] = {};
    for (int k0 = 0; k0 < K; k0 += 16) {
        #pragma unroll
        for (int s = tid; s < 512; s += 256) {
            int r = s >> 2, c4 = s & 3;
            float4 va = *(const float4*)(A + (size_t)(m0 + r) * K + k0 + c4 * 4);
            As[c4 * 4 + 0][r] = va.x; As[c4 * 4 + 1][r] = va.y;
            As[c4 * 4 + 2][r] = va.z; As[c4 * 4 + 3][r] = va.w;
            float4 vb = *(const float4*)(B + (size_t)(n0 + r) * K + k0 + c4 * 4);
            Bs[c4 * 4 + 0][r] = vb.x; Bs[c4 * 4 + 1][r] = vb.y;
            Bs[c4 * 4 + 2][r] = vb.z; Bs[c4 * 4 + 3][r] = vb.w;
        }
        __syncthreads();
        #pragma unroll
        for (int kk = 0; kk < 16; kk++) {
            float a[8], b[8];
            *(float4*)&a[0] = *(const float4*)&As[kk][ty * 8];
            *(float4*)&a[4] = *(const float4*)&As[kk][ty * 8 + 4];
            *(float4*)&b[0] = *(const float4*)&Bs[kk][tx * 8];
            *(float4*)&b[4] = *(const float4*)&Bs[kk][tx * 8 + 4];
            #pragma unroll
            for (int i = 0; i < 8; i++)
                #pragma unroll
                for (int j = 0; j < 8; j++)
                    acc[i][j] = fmaf(a[i], b[j], acc[i][j]);
        }
        __syncthreads();
    }
    float bv[8];
    *(float4*)&bv[0] = *(const float4*)(bias + n0 + tx * 8);
    *(float4*)&bv[4] = *(const float4*)(bias + n0 + tx * 8 + 4);
    #pragma unroll
    for (int i = 0; i < 8; i++) {
        float out[8];
        #pragma unroll
        for (int j = 0; j < 8; j++) {
            float v = acc[i][j] + bv[j];
            if (RELU) v = fmaxf(v, 0.f);
            out[j] = v;
        }
        float* cp = C + (size_t)(m0 + ty * 8 + i) * N + n0 + tx * 8;
        *(float4*)cp = *(float4*)&out[0];
        *(float4*)(cp + 4) = *(float4*)&out[4];
    }
}

// ---------------- fp32 scores (selection-critical, round-1 arithmetic) ----------------
__global__ __launch_bounds__(256)
void scores128_kernel(const float* __restrict__ q, float* __restrict__ pbuf) {
    const int bh = blockIdx.y, b = bh >> 3, h = bh & 7;
    const int x = blockIdx.x;
    const int it = (x >= 6) ? 3 : (x >= 3) ? 2 : (x >= 1) ? 1 : 0;
    const int jt = x - it * (it + 1) / 2;
    const int m0 = it * 128, n0 = jt * 128;
    __shared__ float Qi[64][132];
    __shared__ float Qj[64][132];
    const float* qbase = q + (size_t)b * SEQ * DIM + h * DKH;
    const int tid = threadIdx.x;
    for (int s = tid; s < 2048; s += 256) {
        int row = (s & 15) | ((s >> 8) << 4);
        int c4 = (s >> 4) & 15;
        float4 vi = *(const float4*)(qbase + (size_t)(m0 + row) * DIM + c4 * 4);
        Qi[c4 * 4 + 0][row] = vi.x; Qi[c4 * 4 + 1][row] = vi.y;
        Qi[c4 * 4 + 2][row] = vi.z; Qi[c4 * 4 + 3][row] = vi.w;
        float4 vj = *(const float4*)(qbase + (size_t)(n0 + row) * DIM + c4 * 4);
        Qj[c4 * 4 + 0][row] = vj.x; Qj[c4 * 4 + 1][row] = vj.y;
        Qj[c4 * 4 + 2][row] = vj.z; Qj[c4 * 4 + 3][row] = vj.w;
    }
    __syncthreads();
    const int tx = tid & 15, ty = tid >> 4;
    float acc[8][8] = {};
    #pragma unroll 4
    for (int d = 0; d < 64; d++) {
        float a[8], bb[8];
        *(float4*)&a[0] = *(const float4*)&Qi[d][ty * 8];
        *(float4*)&a[4] = *(const float4*)&Qi[d][ty * 8 + 4];
        *(float4*)&bb[0] = *(const float4*)&Qj[d][tx * 8];
        *(float4*)&bb[4] = *(const float4*)&Qj[d][tx * 8 + 4];
        #pragma unroll
        for (int i = 0; i < 8; i++)
            #pragma unroll
            for (int j = 0; j < 8; j++)
                acc[i][j] = fmaf(a[i], bb[j], acc[i][j]);
    }
    float* prow = pbuf + ((size_t)bh * SEQ + m0) * SEQ + n0;
    #pragma unroll
    for (int i = 0; i < 8; i++) {
        int gi = m0 + ty * 8 + i;
        #pragma unroll
        for (int jq = 0; jq < 2; jq++) {
            float o[4];
            #pragma unroll
            for (int j = 0; j < 4; j++) {
                int gj = n0 + tx * 8 + jq * 4 + j;
                o[j] = (gj < gi) ? acc[i][jq * 4 + j] * 0.125f : NEGV;
            }
            *(float4*)(prow + (size_t)(ty * 8 + i) * SEQ + tx * 8 + jq * 4) = *(float4*)o;
        }
    }
}

// ---------------- lean 3-plane bf16 GEMM (pre-split operands) ----------------
// C[M,N] = A[M,K] @ B[N,K]^T + bias. Bit-identical to mm6's split-6 arithmetic.
// OUTP 0: fp32 C;  OUTP 1: 3-plane bf16 out (for h1).
template <int RELU, int OUTP>
__global__ __launch_bounds__(256) void gemm3p(
    const ushort_t* __restrict__ Apl, size_t Aelems, int lda,
    const ushort_t* __restrict__ Bpl, size_t Belems, int ldb,
    const float* __restrict__ bias,
    float* __restrict__ C, ushort_t* __restrict__ Cpl, size_t Celems,
    int ldc, int K) {
    __shared__ uint4 lds[3072];  // A: 3 planes x 8 frags x 1KB ; B same
    const int tid = threadIdx.x, lane = tid & 63, wid = tid >> 6;
    const int wm = wid >> 1, wn = wid & 1;
    const int m0 = blockIdx.y * 128, n0 = blockIdx.x * 128;
    const int lrow = lane & 15, lkof = (lane >> 4) * 8;
    f32x4 acc[4][4] = {};
    for (int k0 = 0; k0 < K; k0 += 32) {
        #pragma unroll
        for (int t = 0; t < 12; t++) {
            const ushort_t* src;
            int dstoff;
            if (t < 6) {
                int cc = wid + t * 4;             // 0..23
                int p = cc >> 3, fi = cc & 7;
                src = Apl + (size_t)p * Aelems + (size_t)(m0 + fi * 16 + lrow) * lda + k0 + lkof;
                dstoff = p * 512 + fi * 64;
            } else {
                int cc = wid + (t - 6) * 4;       // 0..23
                int p = cc >> 3, fi = cc & 7;
                src = Bpl + (size_t)p * Belems + (size_t)(n0 + fi * 16 + lrow) * ldb + k0 + lkof;
                dstoff = 1536 + p * 512 + fi * 64;
            }
            lds[dstoff + lane] = *(const uint4*)src;
        }
        __syncthreads();
        const bf16x8* ldsb = (const bf16x8*)lds;
        bf16x8 afr[4][3];
        #pragma unroll
        for (int fm = 0; fm < 4; fm++)
            #pragma unroll
            for (int p = 0; p < 3; p++)
                afr[fm][p] = ldsb[p * 512 + (wm * 4 + fm) * 64 + lane];
        #pragma unroll
        for (int fn = 0; fn < 4; fn++) {
            bf16x8 b0 = ldsb[1536 + 0 * 512 + (wn * 4 + fn) * 64 + lane];
            bf16x8 b1 = ldsb[1536 + 1 * 512 + (wn * 4 + fn) * 64 + lane];
            bf16x8 b2 = ldsb[1536 + 2 * 512 + (wn * 4 + fn) * 64 + lane];
            #pragma unroll
            for (int fm = 0; fm < 4; fm++) {
                f32x4 t = acc[fm][fn];
                t = mfma_bf16(afr[fm][0], b0, t);
                t = mfma_bf16(afr[fm][1], b0, t);
                t = mfma_bf16(afr[fm][2], b0, t);
                t = mfma_bf16(afr[fm][0], b1, t);
                t = mfma_bf16(afr[fm][1], b1, t);
                t = mfma_bf16(afr[fm][0], b2, t);
                acc[fm][fn] = t;
            }
        }
        __syncthreads();
    }
    #pragma unroll
    for (int fm = 0; fm < 4; fm++) {
        int row0 = m0 + (wm * 4 + fm) * 16 + (lane >> 4) * 4;
        #pragma unroll
        for (int fn = 0; fn < 4; fn++) {
            int col = n0 + (wn * 4 + fn) * 16 + (lane & 15);
            float bv = bias[col];
            f32x4 a = acc[fm][fn];
            #pragma unroll
            for (int r = 0; r < 4; r++) {
                int row = row0 + r;
                float val = a[r] + bv;
                if (RELU) val = fmaxf(val, 0.f);
                if constexpr (OUTP == 0) {
                    C[(size_t)row * ldc + col] = val;
                } else {
                    unsigned int h0 = bf16_rne(val);
                    float r1 = val - __uint_as_float(h0 << 16);
                    unsigned int h1 = bf16_rne(r1);
                    float r2 = r1 - __uint_as_float(h1 << 16);
                    unsigned int h2 = bf16_rne(r2);
                    size_t o = (size_t)row * ldc + col;
                    Cpl[o] = (ushort_t)h0;
                    Cpl[Celems + o] = (ushort_t)h1;
                    Cpl[2 * Celems + o] = (ushort_t)h2;
                }
            }
        }
    }
}

// ---------------- unified split-6 bf16-MFMA matmul (in-kernel split; fallback + AV) ----------------
template <int MODE, int TN>
__global__ __launch_bounds__(256) void mm6(const float* __restrict__ Aall,
                                           const float* __restrict__ Ball,
                                           float* __restrict__ Call,
                                           const float* __restrict__ bias,
                                           int lda, int ldb, int ldc, int K) {
    constexpr int BFR = TN / 16;
    constexpr int MFR = (TN == 128) ? 4 : 2;
    constexpr int BBASE = 3 * 8 * 64;
    __shared__ uint4 lds[3 * 8 * 64 + 3 * BFR * 64];

    const int tid = threadIdx.x, lane = tid & 63, wid = tid >> 6;
    const int wm = (TN == 128) ? (wid >> 1) : wid;
    const int wn = (TN == 128) ? (wid & 1) : 0;

    const float* A;
    const float* B;
    float* C;
    int m0, n0, kmax;
    if constexpr (MODE <= 1) {
        m0 = blockIdx.y * 128;
        n0 = blockIdx.x * 128;
        A = Aall; B = Ball; C = Call;
        kmax = K;
    } else {
        const int bh = blockIdx.y, b = bh >> 3, h = bh & 7, rb = blockIdx.x;
        m0 = rb * 128; n0 = 0;
        A = Aall + (size_t)bh * SEQ * SEQ;
        B = Ball + (size_t)bh * DKH * SEQ;
        C = Call + ((size_t)b * SEQ) * DIM + h * DKH;
        kmax = rb ? (rb + 1) * 128 : SEQ;
    }

    f32x4 acc[MFR][4] = {};

    for (int k0 = 0; k0 < kmax; k0 += 32) {
        for (int c = tid; c < (8 + BFR) * 64; c += 256) {
            int fi = c >> 6, lc = c & 63;
            const float* src = (fi < 8)
                ? A + (size_t)(m0 + fi * 16 + (lc & 15)) * lda + k0 + (lc >> 4) * 8
                : B + (size_t)(n0 + (fi - 8) * 16 + (lc & 15)) * ldb + k0 + (lc >> 4) * 8;
            float4 x0 = *(const float4*)src;
            float4 x1 = *(const float4*)(src + 4);
            float xs[8] = {x0.x, x0.y, x0.z, x0.w, x1.x, x1.y, x1.z, x1.w};
            unsigned int hh[8], hm[8], hl[8];
            split3_8(xs, hh, hm, hl);
            int base = (fi < 8) ? fi * 64 + lc : BBASE + (fi - 8) * 64 + lc;
            int fstride = (fi < 8) ? 8 * 64 : BFR * 64;
            lds[base + 0 * fstride] = pack8(hh);
            lds[base + 1 * fstride] = pack8(hm);
            lds[base + 2 * fstride] = pack8(hl);
        }
        __syncthreads();

        const bf16x8* ldsb = (const bf16x8*)lds;
        bf16x8 afr[MFR][3];
        #pragma unroll
        for (int fm = 0; fm < MFR; fm++)
            #pragma unroll
            for (int p = 0; p < 3; p++)
                afr[fm][p] = ldsb[p * 512 + (wm * MFR + fm) * 64 + lane];
        #pragma unroll
        for (int fn = 0; fn < 4; fn++) {
            bf16x8 b0 = ldsb[BBASE + 0 * (BFR * 64) + (wn * 4 + fn) * 64 + lane];
            bf16x8 b1 = ldsb[BBASE + 1 * (BFR * 64) + (wn * 4 + fn) * 64 + lane];
            bf16x8 b2 = ldsb[BBASE + 2 * (BFR * 64) + (wn * 4 + fn) * 64 + lane];
            #pragma unroll
            for (int fm = 0; fm < MFR; fm++) {
                f32x4 t = acc[fm][fn];
                t = mfma_bf16(afr[fm][0], b0, t);
                t = mfma_bf16(afr[fm][1], b0, t);
                t = mfma_bf16(afr[fm][2], b0, t);
                t = mfma_bf16(afr[fm][0], b1, t);
                t = mfma_bf16(afr[fm][1], b1, t);
                t = mfma_bf16(afr[fm][0], b2, t);
                acc[fm][fn] = t;
            }
        }
        __syncthreads();
    }

    #pragma unroll
    for (int fm = 0; fm < MFR; fm++) {
        int row0 = m0 + (wm * MFR + fm) * 16 + (lane >> 4) * 4;
        #pragma unroll
        for (int fn = 0; fn < 4; fn++) {
            int col = n0 + (wn * 4 + fn) * 16 + (lane & 15);
            float bv = 0.f;
            if constexpr (MODE <= 1) bv = bias[col];
            f32x4 a = acc[fm][fn];
            #pragma unroll
            for (int r = 0; r < 4; r++) {
                int row = row0 + r;
                float val;
                if constexpr (MODE == 0) val = a[r] + bv;
                else if constexpr (MODE == 1) val = fmaxf(a[r] + bv, 0.f);
                else val = (row == 0) ? 0.f : a[r];
                C[(size_t)row * ldc + col] = val;
            }
        }
    }
}

// ---------------- AV with plane output (new path) ----------------
// per (b,h): o = W @ Vt^T, row0 zeroed; emits 3 bf16 planes of o (head-interleaved).
__global__ __launch_bounds__(256) void mm6av_pl(const float* __restrict__ pbuf,
                                                const float* __restrict__ vt,
                                                ushort_t* __restrict__ Opl, size_t Oelems) {
    constexpr int BFR = 4, MFR = 2, BBASE = 3 * 8 * 64;
    __shared__ uint4 lds[3 * 8 * 64 + 3 * BFR * 64];
    const int tid = threadIdx.x, lane = tid & 63, wid = tid >> 6;
    const int bh = blockIdx.y, b = bh >> 3, h = bh & 7, rb = blockIdx.x;
    const int m0 = rb * 128;
    const float* A = pbuf + (size_t)bh * SEQ * SEQ;
    const float* B = vt + (size_t)bh * DKH * SEQ;
    const int kmax = rb ? (rb + 1) * 128 : SEQ;

    f32x4 acc[MFR][4] = {};
    for (int k0 = 0; k0 < kmax; k0 += 32) {
        for (int c = tid; c < (8 + BFR) * 64; c += 256) {
            int fi = c >> 6, lc = c & 63;
            const float* src = (fi < 8)
                ? A + (size_t)(m0 + fi * 16 + (lc & 15)) * SEQ + k0 + (lc >> 4) * 8
                : B + (size_t)((fi - 8) * 16 + (lc & 15)) * SEQ + k0 + (lc >> 4) * 8;
            float4 x0 = *(const float4*)src;
            float4 x1 = *(const float4*)(src + 4);
            float xs[8] = {x0.x, x0.y, x0.z, x0.w, x1.x, x1.y, x1.z, x1.w};
            unsigned int hh[8], hm[8], hl[8];
            split3_8(xs, hh, hm, hl);
            int base = (fi < 8) ? fi * 64 + lc : BBASE + (fi - 8) * 64 + lc;
            int fstride = (fi < 8) ? 8 * 64 : BFR * 64;
            lds[base + 0 * fstride] = pack8(hh);
            lds[base + 1 * fstride] = pack8(hm);
            lds[base + 2 * fstride] = pack8(hl);
        }
        __syncthreads();
        const bf16x8* ldsb = (const bf16x8*)lds;
        bf16x8 afr[MFR][3];
        #pragma unroll
        for (int fm = 0; fm < MFR; fm++)
            #pragma unroll
            for (int p = 0; p < 3; p++)
                afr[fm][p] = ldsb[p * 512 + (wid * MFR + fm) * 64 + lane];
        #pragma unroll
        for (int fn = 0; fn < 4; fn++) {
            bf16x8 b0 = ldsb[BBASE + 0 * (BFR * 64) + fn * 64 + lane];
            bf16x8 b1 = ldsb[BBASE + 1 * (BFR * 64) + fn * 64 + lane];
            bf16x8 b2 = ldsb[BBASE + 2 * (BFR * 64) + fn * 64 + lane];
            #pragma unroll
            for (int fm = 0; fm < MFR; fm++) {
                f32x4 t = acc[fm][fn];
                t = mfma_bf16(afr[fm][0], b0, t);
                t = mfma_bf16(afr[fm][1], b0, t);
                t = mfma_bf16(afr[fm][2], b0, t);
                t = mfma_bf16(afr[fm][0], b1, t);
                t = mfma_bf16(afr[fm][1], b1, t);
                t = mfma_bf16(afr[fm][0], b2, t);
                acc[fm][fn] = t;
            }
        }
        __syncthreads();
    }
    #pragma unroll
    for (int fm = 0; fm < MFR; fm++) {
        int row0 = m0 + (wid * MFR + fm) * 16 + (lane >> 4) * 4;
        #pragma unroll
        for (int fn = 0; fn < 4; fn++) {
            int col = fn * 16 + (lane & 15);
            f32x4 a = acc[fm][fn];
            #pragma unroll
            for (int r = 0; r < 4; r++) {
                int row = row0 + r;
                float val = (row == 0) ? 0.f : a[r];
                unsigned int h0 = bf16_rne(val);
                float r1 = val - __uint_as_float(h0 << 16);
                unsigned int h1 = bf16_rne(r1);
                float r2 = r1 - __uint_as_float(h1 << 16);
                unsigned int h2 = bf16_rne(r2);
                size_t o = ((size_t)b * SEQ + row) * DIM + h * DKH + col;
                Opl[o] = (ushort_t)h0;
                Opl[Oelems + o] = (ushort_t)h1;
                Opl[2 * Oelems + o] = (ushort_t)h2;
            }
        }
    }
}

// ---------------- V transpose ----------------
__global__ __launch_bounds__(256) void transpose_v_kernel(const float* __restrict__ v,
                                                          float* __restrict__ vt) {
    const int bh = blockIdx.y, jt = blockIdx.x;
    const int b = bh >> 3, h = bh & 7;
    __shared__ float L[64][65];
    const int tid = threadIdx.x;
    for (int s = tid; s < 1024; s += 256) {
        int jj = s >> 4, d4 = s & 15;
        float4 x = *(const float4*)(v + ((size_t)(b * SEQ) + jt * 64 + jj) * DIM + h * DKH + d4 * 4);
        L[jj][d4 * 4 + 0] = x.x; L[jj][d4 * 4 + 1] = x.y;
        L[jj][d4 * 4 + 2] = x.z; L[jj][d4 * 4 + 3] = x.w;
    }
    __syncthreads();
    int d = tid >> 2, jq = tid & 3;
    float* dst = vt + ((size_t)bh * DKH + d) * SEQ + jt * 64 + jq * 16;
    #pragma unroll
    for (int c4 = 0; c4 < 4; c4++) {
        float4 o = make_float4(L[jq * 16 + c4 * 4 + 0][d], L[jq * 16 + c4 * 4 + 1][d],
                               L[jq * 16 + c4 * 4 + 2][d], L[jq * 16 + c4 * 4 + 3][d]);
        *(float4*)(dst + c4 * 4) = o;
    }
}

// ---------------- softmax -> top5 -> second softmax ----------------
__global__ __launch_bounds__(64)
void softmax_topk_kernel(float* __restrict__ pbuf) {
    const int i = blockIdx.x;
    const size_t row = (size_t)blockIdx.y * SEQ + i;
    const int lane = threadIdx.x;
    float* p = pbuf + row * SEQ;
    float v[8];
    {
        int j0 = lane * 4;
        if (j0 < i) {
            float4 x0 = *(const float4*)(p + j0);
            v[0] = (j0 + 0 < i) ? x0.x : NEGV;
            v[1] = (j0 + 1 < i) ? x0.y : NEGV;
            v[2] = (j0 + 2 < i) ? x0.z : NEGV;
            v[3] = (j0 + 3 < i) ? x0.w : NEGV;
        } else { v[0] = v[1] = v[2] = v[3] = NEGV; }
        int j1 = 256 + j0;
        if (j1 < i) {
            float4 x1 = *(const float4*)(p + j1);
            v[4] = (j1 + 0 < i) ? x1.x : NEGV;
            v[5] = (j1 + 1 < i) ? x1.y : NEGV;
            v[6] = (j1 + 2 < i) ? x1.z : NEGV;
            v[7] = (j1 + 3 < i) ? x1.w : NEGV;
        } else { v[4] = v[5] = v[6] = v[7] = NEGV; }
    }
    float lm = v[0];
    #pragma unroll
    for (int e = 1; e < 8; e++) lm = fmaxf(lm, v[e]);
    float m1 = wmaxf(lm);
    float ls = 0.f;
    #pragma unroll
    for (int e = 0; e < 8; e++) { v[e] = expf(v[e] - m1); ls += v[e]; }
    float Z = wsumf(ls);
    #pragma unroll
    for (int e = 0; e < 8; e++) v[e] = v[e] / Z;
    float thr = -INFINITY;
    if (i >= KIDX) {
        int remaining = KIDX;
        float cut = INFINITY;
        #pragma unroll 1
        for (int iter = 0; iter < KIDX; iter++) {
            float l2 = -INFINITY;
            #pragma unroll
            for (int e = 0; e < 8; e++) if (v[e] < cut) l2 = fmaxf(l2, v[e]);
            float m2 = wmaxf(l2);
            int lc = 0;
            #pragma unroll
            for (int e = 0; e < 8; e++) if (v[e] == m2) lc++;
            int c = wsumi(lc);
            if (c >= remaining) { thr = m2; break; }
            remaining -= c; cut = m2;
        }
    }
    float lpm = v[0];
    #pragma unroll
    for (int e = 1; e < 8; e++) lpm = fmaxf(lpm, v[e]);
    float pm = wmaxf(lpm);
    float t[8];
    float ls2 = 0.f;
    #pragma unroll
    for (int e = 0; e < 8; e++) {
        bool keep = (i >= KIDX) ? (v[e] >= thr) : true;
        t[e] = keep ? expf(v[e] - pm) : 0.f;
        ls2 += t[e];
    }
    float Z2 = wsumf(ls2);
    #pragma unroll
    for (int e = 0; e < 8; e++) t[e] = t[e] / Z2;
    *(float4*)(p + lane * 4) = make_float4(t[0], t[1], t[2], t[3]);
    *(float4*)(p + 256 + lane * 4) = make_float4(t[4], t[5], t[6], t[7]);
}

// ---------------- dst = LN(x + t)  (EMIT: also write 3 bf16 planes of dst) ----------------
template <int EMIT>
__global__ __launch_bounds__(64)
void add_ln_kernel(const float* __restrict__ x, const float* __restrict__ t,
                   const float* __restrict__ w, const float* __restrict__ b,
                   float* __restrict__ dst, ushort_t* __restrict__ dpl, size_t delems) {
    const size_t row = blockIdx.x;
    const int lane = threadIdx.x;
    const float* xr = x + row * DIM;
    const float* tr = t + row * DIM;
    float v[8];
    {
        float4 a0 = *(const float4*)(xr + lane * 4);
        float4 t0 = *(const float4*)(tr + lane * 4);
        float4 a1 = *(const float4*)(xr + 256 + lane * 4);
        float4 t1 = *(const float4*)(tr + 256 + lane * 4);
        v[0] = a0.x + t0.x; v[1] = a0.y + t0.y; v[2] = a0.z + t0.z; v[3] = a0.w + t0.w;
        v[4] = a1.x + t1.x; v[5] = a1.y + t1.y; v[6] = a1.z + t1.z; v[7] = a1.w + t1.w;
    }
    float ls = 0.f;
    #pragma unroll
    for (int e = 0; e < 8; e++) ls += v[e];
    float mean = wsumf(ls) / (float)DIM;
    float ld = 0.f;
    #pragma unroll
    for (int e = 0; e < 8; e++) { float d = v[e] - mean; ld += d * d; }
    float var = wsumf(ld) / (float)DIM;
    float den = sqrtf(var + 1e-5f);
    float wv[8], bv[8];
    *(float4*)&wv[0] = *(const float4*)(w + lane * 4);
    *(float4*)&wv[4] = *(const float4*)(w + 256 + lane * 4);
    *(float4*)&bv[0] = *(const float4*)(b + lane * 4);
    *(float4*)&bv[4] = *(const float4*)(b + 256 + lane * 4);
    float o[8];
    #pragma unroll
    for (int e = 0; e < 8; e++) o[e] = (v[e] - mean) / den * wv[e] + bv[e];
    float* dr = dst + row * DIM;
    *(float4*)(dr + lane * 4) = make_float4(o[0], o[1], o[2], o[3]);
    *(float4*)(dr + 256 + lane * 4) = make_float4(o[4], o[5], o[6], o[7]);
    if constexpr (EMIT) {
        unsigned int hh[8], hm[8], hl[8];
        split3_8(o, hh, hm, hl);
        size_t base0 = row * DIM + lane * 4;
        size_t base1 = base0 + 256;
        #pragma unroll
        for (int p = 0; p < 3; p++) {
            const unsigned int* hp = (p == 0) ? hh : (p == 1) ? hm : hl;
            *(uint2*)(dpl + p * delems + base0) =
                make_uint2(hp[0] | (hp[1] << 16), hp[2] | (hp[3] << 16));
            *(uint2*)(dpl + p * delems + base1) =
                make_uint2(hp[4] | (hp[5] << 16), hp[6] | (hp[7] << 16));
        }
    }
}

extern "C" void kernel_launch(void* const* d_in, const int* in_sizes, int n_in,
                              void* d_out, int out_size, void* d_ws, size_t ws_size,
                              hipStream_t stream) {
    const float* q_embed = (const float*)d_in[0];
    const float* qa_embed = (const float*)d_in[1];
    const float* pe = (const float*)d_in[2];
    const float* Wk = (const float*)d_in[3];
    const float* bk = (const float*)d_in[4];
    const float* Wv = (const float*)d_in[5];
    const float* bv = (const float*)d_in[6];
    const float* Wo = (const float*)d_in[7];
    const float* bo = (const float*)d_in[8];
    const float* W1 = (const float*)d_in[9];
    const float* b1 = (const float*)d_in[10];
    const float* W2 = (const float*)d_in[11];
    const float* b2 = (const float*)d_in[12];
    const float* ln1w = (const float*)d_in[13];
    const float* ln1b = (const float*)d_in[14];
    const float* ln2w = (const float*)d_in[15];
    const float* ln2b = (const float*)d_in[16];

    float* outx = (float*)d_out;
    const size_t NE = (size_t)BSZ * SEQ * DIM;   // 8388608
    float* pbuf = outx + NE;
    float* ws = (float*)d_ws;
    const int M = BSZ * SEQ;

    const size_t need_new = 13 * NE * sizeof(float);  // ~436 MB
    if (ws_size >= need_new) {
        // ===================== NEW PATH: pre-split planes =====================
        float* xbuf = ws;
        float* qbuf = ws + NE;
        float* vbuf = ws + 2 * NE;
        ushort_t* y_pl = (ushort_t*)(ws + 3 * NE);
        ushort_t* x_pl = (ushort_t*)(ws + 4 * NE + NE / 2);
        ushort_t* w_pl = (ushort_t*)(ws + 6 * NE);
        float* vt = ws + 7 * NE;
        ushort_t* o_pl = (ushort_t*)(ws + 8 * NE);
        ushort_t* h1_pl = (ushort_t*)(ws + 7 * NE);

        const size_t WVE = (size_t)DIM * DIM;      // 262144
        const size_t W1E = (size_t)DFFN * DIM;     // 1048576
        const size_t LW = 3 * (WVE + WVE + W1E + W1E);  // ushorts per layer

        // weight pre-splits
        for (int l = 0; l < NL; l++) {
            ushort_t* base = w_pl + (size_t)l * LW;
            split3w<<<(int)(WVE / 8 + 255) / 256, 256, 0, stream>>>(
                Wv + (size_t)l * WVE, base, WVE, (int)(WVE / 8));
            split3w<<<(int)(WVE / 8 + 255) / 256, 256, 0, stream>>>(
                Wo + (size_t)l * WVE, base + 3 * WVE, WVE, (int)(WVE / 8));
            split3w<<<(int)(W1E / 8 + 255) / 256, 256, 0, stream>>>(
                W1 + (size_t)l * W1E, base + 6 * WVE, W1E, (int)(W1E / 8));
            split3w<<<(int)(W1E / 8 + 255) / 256, 256, 0, stream>>>(
                W2 + (size_t)l * W1E, base + 6 * WVE + 3 * W1E, W1E, (int)(W1E / 8));
        }

        add_pe_new<<<(int)(NE / 8 + 255) / 256, 256, 0, stream>>>(
            q_embed, qa_embed, pe, xbuf, y_pl, NE, (int)(NE / 8));

        for (int l = 0; l < NL; l++) {
            ushort_t* wb = w_pl + (size_t)l * LW;
            ushort_t* Wv_pl = wb;
            ushort_t* Wo_pl = wb + 3 * WVE;
            ushort_t* W1_pl = wb + 6 * WVE;
            ushort_t* W2_pl = wb + 6 * WVE + 3 * W1E;

            gemm_bt<0><<<dim3(DIM / 128, M / 128), 256, 0, stream>>>(
                xbuf, Wk + (size_t)l * WVE, bk + (size_t)l * DIM, qbuf, M, DIM, DIM);
            gemm3p<0, 0><<<dim3(DIM / 128, M / 128), 256, 0, stream>>>(
                y_pl, NE, DIM, Wv_pl, WVE, DIM, bv + (size_t)l * DIM,
                vbuf, nullptr, 0, DIM, DIM);
            transpose_v_kernel<<<dim3(8, BSZ * NH), 256, 0, stream>>>(vbuf, vt);
            scores128_kernel<<<dim3(10, BSZ * NH), 256, 0, stream>>>(qbuf, pbuf);
            softmax_topk_kernel<<<dim3(SEQ, BSZ * NH), 64, 0, stream>>>(pbuf);
            mm6av_pl<<<dim3(4, BSZ * NH), 256, 0, stream>>>(pbuf, vt, o_pl, NE);
            gemm3p<0, 0><<<dim3(DIM / 128, M / 128), 256, 0, stream>>>(
                o_pl, NE, DIM, Wo_pl, WVE, DIM, bo + (size_t)l * DIM,
                qbuf, nullptr, 0, DIM, DIM);
            add_ln_kernel<1><<<M, 64, 0, stream>>>(
                xbuf, qbuf, ln1w + (size_t)l * DIM, ln1b + (size_t)l * DIM,
                xbuf, x_pl, NE);
            gemm3p<1, 1><<<dim3(DFFN / 128, M / 128), 256, 0, stream>>>(
                x_pl, NE, DIM, W1_pl, W1E, DIM, b1 + (size_t)l * DFFN,
                nullptr, h1_pl, (size_t)M * DFFN, DFFN, DIM);
            gemm3p<0, 0><<<dim3(DIM / 128, M / 128), 256, 0, stream>>>(
                h1_pl, (size_t)M * DFFN, DFFN, W2_pl, W1E, DFFN, b2 + (size_t)l * DIM,
                vbuf, nullptr, 0, DIM, DFFN);
            float* dst = (l == NL - 1) ? outx : xbuf;
            add_ln_kernel<0><<<M, 64, 0, stream>>>(
                xbuf, vbuf, ln2w + (size_t)l * DIM, ln2b + (size_t)l * DIM,
                dst, nullptr, 0);
        }
    } else {
        // ===================== FALLBACK: round-4 path =====================
        float* xbuf = ws;
        float* ybuf = ws + NE;
        float* qbuf = ws + 2 * NE;
        float* vbuf = ws + 3 * NE;
        float* obuf = ws + 4 * NE;
        float* vtbuf = ws + 5 * NE;
        float* h1buf = ws + 5 * NE;

        {
            int n4 = (int)(NE / 4);
            add_pe_old<<<(n4 + 255) / 256, 256, 0, stream>>>(
                (const float4*)q_embed, (const float4*)qa_embed, (const float4*)pe,
                (float4*)xbuf, (float4*)ybuf, n4);
        }
        for (int l = 0; l < NL; l++) {
            const float* Wk_l = Wk + (size_t)l * DIM * DIM;
            const float* Wv_l = Wv + (size_t)l * DIM * DIM;
            const float* Wo_l = Wo + (size_t)l * DIM * DIM;
            const float* W1_l = W1 + (size_t)l * DFFN * DIM;
            const float* W2_l = W2 + (size_t)l * DIM * DFFN;

            gemm_bt<0><<<dim3(DIM / 128, M / 128), 256, 0, stream>>>(
                xbuf, Wk_l, bk + (size_t)l * DIM, qbuf, M, DIM, DIM);
            mm6<0, 128><<<dim3(DIM / 128, M / 128), 256, 0, stream>>>(
                ybuf, Wv_l, vbuf, bv + (size_t)l * DIM, DIM, DIM, DIM, DIM);
            transpose_v_kernel<<<dim3(8, BSZ * NH), 256, 0, stream>>>(vbuf, vtbuf);
            scores128_kernel<<<dim3(10, BSZ * NH), 256, 0, stream>>>(qbuf, pbuf);
            softmax_topk_kernel<<<dim3(SEQ, BSZ * NH), 64, 0, stream>>>(pbuf);
            mm6<3, 64><<<dim3(4, BSZ * NH), 256, 0, stream>>>(
                pbuf, vtbuf, obuf, nullptr, SEQ, SEQ, DIM, SEQ);
            mm6<0, 128><<<dim3(DIM / 128, M / 128), 256, 0, stream>>>(
                obuf, Wo_l, qbuf, bo + (size_t)l * DIM, DIM, DIM, DIM, DIM);
            add_ln_kernel<0><<<M, 64, 0, stream>>>(
                xbuf, qbuf, ln1w + (size_t)l * DIM, ln1b + (size_t)l * DIM,
                xbuf, nullptr, 0);
            mm6<1, 128><<<dim3(DFFN / 128, M / 128), 256, 0, stream>>>(
                xbuf, W1_l, h1buf, b1 + (size_t)l * DFFN, DIM, DIM, DFFN, DIM);
            mm6<0, 128><<<dim3(DIM / 128, M / 128), 256, 0, stream>>>(
                h1buf, W2_l, vbuf, b2 + (size_t)l * DIM, DFFN, DFFN, DIM, DFFN);
            float* dst = (l == NL - 1) ? outx : xbuf;
            add_ln_kernel<0><<<M, 64, 0, stream>>>(
                xbuf, vbuf, ln2w + (size_t)l * DIM, ln2b + (size_t)l * DIM,
                dst, nullptr, 0);
        }
    }
}

// Round 6
// 1969.580 us; speedup vs baseline: 1.9379x; 1.1137x over previous
//
#include <hip/hip_runtime.h>
#include <hip/hip_bf16.h>
#include <math.h>

#define BSZ 32
#define SEQ 512
#define DIM 512
#define NH 8
#define DKH 64
#define DFFN 2048
#define NL 2
#define KIDX 5
#define NEGV -1e32f

typedef float f32x4 __attribute__((ext_vector_type(4)));
typedef short bf16x8 __attribute__((ext_vector_type(8)));
typedef unsigned short ushort_t;
typedef __attribute__((address_space(1))) void gvoid;
typedef __attribute__((address_space(3))) void lvoid;

// async global->LDS, 16B per lane; dest must be wave-uniform base (+lane*16 by HW)
__device__ __forceinline__ void gload_lds16(const void* g, void* l) {
    __builtin_amdgcn_global_load_lds((gvoid*)(uintptr_t)g, (lvoid*)l, 16, 0, 0);
}

// ---------------- wave (64-lane) reduce helpers ----------------
__device__ __forceinline__ float wmaxf(float v) {
    #pragma unroll
    for (int m = 32; m > 0; m >>= 1) v = fmaxf(v, __shfl_xor(v, m));
    return v;
}
__device__ __forceinline__ float wsumf(float v) {
    #pragma unroll
    for (int m = 32; m > 0; m >>= 1) v += __shfl_xor(v, m);
    return v;
}
__device__ __forceinline__ int wsumi(int v) {
    #pragma unroll
    for (int m = 32; m > 0; m >>= 1) v += __shfl_xor(v, m);
    return v;
}

// ---------------- bf16 split helpers ----------------
__device__ __forceinline__ unsigned int bf16_rne(float x) {
    unsigned int u = __float_as_uint(x);
    return (u + 0x7fffu + ((u >> 16) & 1u)) >> 16;
}
__device__ __forceinline__ void split3_8(const float* xs, unsigned int* hh,
                                         unsigned int* hm, unsigned int* hl) {
    #pragma unroll
    for (int e = 0; e < 8; e++) {
        float x = xs[e];
        unsigned int h0 = bf16_rne(x);
        float r1 = x - __uint_as_float(h0 << 16);
        unsigned int h1 = bf16_rne(r1);
        float r2 = r1 - __uint_as_float(h1 << 16);
        hh[e] = h0; hm[e] = h1; hl[e] = bf16_rne(r2);
    }
}
__device__ __forceinline__ uint4 pack8(const unsigned int* h) {
    return make_uint4(h[0] | (h[1] << 16), h[2] | (h[3] << 16),
                      h[4] | (h[5] << 16), h[6] | (h[7] << 16));
}

__device__ __forceinline__ f32x4 mfma_bf16(bf16x8 a, bf16x8 b, f32x4 c) {
    return __builtin_amdgcn_mfma_f32_16x16x32_bf16(a, b, c, 0, 0, 0);
}

// ---------------- add_pe: old (x,y fp32) and new (x fp32 + y planes) ----------------
__global__ void add_pe_old(const float4* __restrict__ q, const float4* __restrict__ qa,
                           const float4* __restrict__ pe, float4* __restrict__ x,
                           float4* __restrict__ y, int n4) {
    int i = blockIdx.x * 256 + threadIdx.x;
    if (i >= n4) return;
    int pi = i & (SEQ * DIM / 4 - 1);
    float4 p = pe[pi];
    float4 a = q[i], b = qa[i];
    x[i] = make_float4(a.x + p.x, a.y + p.y, a.z + p.z, a.w + p.w);
    y[i] = make_float4(b.x + p.x, b.y + p.y, b.z + p.z, b.w + p.w);
}

__global__ void add_pe_new(const float* __restrict__ q, const float* __restrict__ qa,
                           const float* __restrict__ pe, float* __restrict__ x,
                           ushort_t* __restrict__ ypl, size_t yelems, int n8) {
    int i = blockIdx.x * 256 + threadIdx.x;
    if (i >= n8) return;
    size_t base = (size_t)i * 8;
    size_t pb = base & (size_t)(SEQ * DIM - 1);
    float4 a0 = *(const float4*)(q + base), a1 = *(const float4*)(q + base + 4);
    float4 b0 = *(const float4*)(qa + base), b1 = *(const float4*)(qa + base + 4);
    float4 p0 = *(const float4*)(pe + pb), p1 = *(const float4*)(pe + pb + 4);
    float4 x0 = make_float4(a0.x + p0.x, a0.y + p0.y, a0.z + p0.z, a0.w + p0.w);
    float4 x1 = make_float4(a1.x + p1.x, a1.y + p1.y, a1.z + p1.z, a1.w + p1.w);
    *(float4*)(x + base) = x0;
    *(float4*)(x + base + 4) = x1;
    float ys[8] = {b0.x + p0.x, b0.y + p0.y, b0.z + p0.z, b0.w + p0.w,
                   b1.x + p1.x, b1.y + p1.y, b1.z + p1.z, b1.w + p1.w};
    unsigned int hh[8], hm[8], hl[8];
    split3_8(ys, hh, hm, hl);
    *(uint4*)(ypl + base) = pack8(hh);
    *(uint4*)(ypl + yelems + base) = pack8(hm);
    *(uint4*)(ypl + 2 * yelems + base) = pack8(hl);
}

// ---------------- weight pre-split: fp32 -> 3 bf16 planes ----------------
__global__ void split3w(const float* __restrict__ W, ushort_t* __restrict__ out,
                        size_t elems, int n8) {
    int i = blockIdx.x * 256 + threadIdx.x;
    if (i >= n8) return;
    size_t base = (size_t)i * 8;
    float4 a0 = *(const float4*)(W + base), a1 = *(const float4*)(W + base + 4);
    float xs[8] = {a0.x, a0.y, a0.z, a0.w, a1.x, a1.y, a1.z, a1.w};
    unsigned int hh[8], hm[8], hl[8];
    split3_8(xs, hh, hm, hl);
    *(uint4*)(out + base) = pack8(hh);
    *(uint4*)(out + elems + base) = pack8(hm);
    *(uint4*)(out + 2 * elems + base) = pack8(hl);
}

// ---------------- fp32 vector GEMM (round-1 exact arithmetic, selection-critical) ----------------
template <int RELU>
__global__ __launch_bounds__(256)
void gemm_bt(const float* __restrict__ A, const float* __restrict__ B,
             const float* __restrict__ bias, float* __restrict__ C,
             int M, int N, int K) {
    __shared__ float As[16][132];
    __shared__ float Bs[16][132];
    const int tid = threadIdx.x;
    const int tx = tid & 15, ty = tid >> 4;
    const int m0 = blockIdx.y * 128, n0 = blockIdx.x * 128;
    float acc[8][8] = {};
    for (int k0 = 0; k0 < K; k0 += 16) {
        #pragma unroll
        for (int s = tid; s < 512; s += 256) {
            int r = s >> 2, c4 = s & 3;
            float4 va = *(const float4*)(A + (size_t)(m0 + r) * K + k0 + c4 * 4);
            As[c4 * 4 + 0][r] = va.x; As[c4 * 4 + 1][r] = va.y;
            As[c4 * 4 + 2][r] = va.z; As[c4 * 4 + 3][r] = va.w;
            float4 vb = *(const float4*)(B + (size_t)(n0 + r) * K + k0 + c4 * 4);
            Bs[c4 * 4 + 0][r] = vb.x; Bs[c4 * 4 + 1][r] = vb.y;
            Bs[c4 * 4 + 2][r] = vb.z; Bs[c4 * 4 + 3][r] = vb.w;
        }
        __syncthreads();
        #pragma unroll
        for (int kk = 0; kk < 16; kk++) {
            float a[8], b[8];
            *(float4*)&a[0] = *(const float4*)&As[kk][ty * 8];
            *(float4*)&a[4] = *(const float4*)&As[kk][ty * 8 + 4];
            *(float4*)&b[0] = *(const float4*)&Bs[kk][tx * 8];
            *(float4*)&b[4] = *(const float4*)&Bs[kk][tx * 8 + 4];
            #pragma unroll
            for (int i = 0; i < 8; i++)
                #pragma unroll
                for (int j = 0; j < 8; j++)
                    acc[i][j] = fmaf(a[i], b[j], acc[i][j]);
        }
        __syncthreads();
    }
    float bv[8];
    *(float4*)&bv[0] = *(const float4*)(bias + n0 + tx * 8);
    *(float4*)&bv[4] = *(const float4*)(bias + n0 + tx * 8 + 4);
    #pragma unroll
    for (int i = 0; i < 8; i++) {
        float out[8];
        #pragma unroll
        for (int j = 0; j < 8; j++) {
            float v = acc[i][j] + bv[j];
            if (RELU) v = fmaxf(v, 0.f);
            out[j] = v;
        }
        float* cp = C + (size_t)(m0 + ty * 8 + i) * N + n0 + tx * 8;
        *(float4*)cp = *(float4*)&out[0];
        *(float4*)(cp + 4) = *(float4*)&out[4];
    }
}

// ---------------- fp32 scores (selection-critical, round-1 arithmetic) ----------------
__global__ __launch_bounds__(256)
void scores128_kernel(const float* __restrict__ q, float* __restrict__ pbuf) {
    const int bh = blockIdx.y, b = bh >> 3, h = bh & 7;
    const int x = blockIdx.x;
    const int it = (x >= 6) ? 3 : (x >= 3) ? 2 : (x >= 1) ? 1 : 0;
    const int jt = x - it * (it + 1) / 2;
    const int m0 = it * 128, n0 = jt * 128;
    __shared__ float Qi[64][132];
    __shared__ float Qj[64][132];
    const float* qbase = q + (size_t)b * SEQ * DIM + h * DKH;
    const int tid = threadIdx.x;
    for (int s = tid; s < 2048; s += 256) {
        int row = (s & 15) | ((s >> 8) << 4);
        int c4 = (s >> 4) & 15;
        float4 vi = *(const float4*)(qbase + (size_t)(m0 + row) * DIM + c4 * 4);
        Qi[c4 * 4 + 0][row] = vi.x; Qi[c4 * 4 + 1][row] = vi.y;
        Qi[c4 * 4 + 2][row] = vi.z; Qi[c4 * 4 + 3][row] = vi.w;
        float4 vj = *(const float4*)(qbase + (size_t)(n0 + row) * DIM + c4 * 4);
        Qj[c4 * 4 + 0][row] = vj.x; Qj[c4 * 4 + 1][row] = vj.y;
        Qj[c4 * 4 + 2][row] = vj.z; Qj[c4 * 4 + 3][row] = vj.w;
    }
    __syncthreads();
    const int tx = tid & 15, ty = tid >> 4;
    float acc[8][8] = {};
    #pragma unroll 4
    for (int d = 0; d < 64; d++) {
        float a[8], bb[8];
        *(float4*)&a[0] = *(const float4*)&Qi[d][ty * 8];
        *(float4*)&a[4] = *(const float4*)&Qi[d][ty * 8 + 4];
        *(float4*)&bb[0] = *(const float4*)&Qj[d][tx * 8];
        *(float4*)&bb[4] = *(const float4*)&Qj[d][tx * 8 + 4];
        #pragma unroll
        for (int i = 0; i < 8; i++)
            #pragma unroll
            for (int j = 0; j < 8; j++)
                acc[i][j] = fmaf(a[i], bb[j], acc[i][j]);
    }
    float* prow = pbuf + ((size_t)bh * SEQ + m0) * SEQ + n0;
    #pragma unroll
    for (int i = 0; i < 8; i++) {
        int gi = m0 + ty * 8 + i;
        #pragma unroll
        for (int jq = 0; jq < 2; jq++) {
            float o[4];
            #pragma unroll
            for (int j = 0; j < 4; j++) {
                int gj = n0 + tx * 8 + jq * 4 + j;
                o[j] = (gj < gi) ? acc[i][jq * 4 + j] * 0.125f : NEGV;
            }
            *(float4*)(prow + (size_t)(ty * 8 + i) * SEQ + tx * 8 + jq * 4) = *(float4*)o;
        }
    }
}

// ---------------- lean NP-plane bf16 GEMM (pre-split operands, async staging) ----------------
// C[M,N] = A[M,K] @ B[N,K]^T + bias. NP=3: 6 products (bit-identical to round-5);
// NP=2: 3 products (layer-2 only). OUTP 1: emit NP bf16 planes of C.
template <int RELU, int OUTP, int NP>
__global__ __launch_bounds__(256) void gemm3p(
    const ushort_t* __restrict__ Apl, size_t Aelems, int lda,
    const ushort_t* __restrict__ Bpl, size_t Belems, int ldb,
    const float* __restrict__ bias,
    float* __restrict__ C, ushort_t* __restrict__ Cpl, size_t Celems,
    int ldc, int K) {
    constexpr int BB = NP * 512;               // uint4 idx of B region
    __shared__ uint4 lds[2 * NP * 512];
    const int tid = threadIdx.x, lane = tid & 63, wid = tid >> 6;
    const int wm = wid >> 1, wn = wid & 1;
    const int m0 = blockIdx.y * 128, n0 = blockIdx.x * 128;
    const int lrow = lane & 15, lkof = (lane >> 4) * 8;
    f32x4 acc[4][4] = {};
    for (int k0 = 0; k0 < K; k0 += 32) {
        #pragma unroll
        for (int t = 0; t < 4 * NP; t++) {
            int cc = wid + t * 4;              // 0 .. 16*NP-1
            bool isB = cc >= 8 * NP;
            int c2 = isB ? (cc - 8 * NP) : cc;
            int p = c2 >> 3, fi = c2 & 7;
            const ushort_t* pb = isB ? (Bpl + (size_t)p * Belems) : (Apl + (size_t)p * Aelems);
            int ld = isB ? ldb : lda;
            int r0 = isB ? n0 : m0;
            const ushort_t* src = pb + (size_t)(r0 + fi * 16 + lrow) * ld + k0 + lkof;
            gload_lds16(src, &lds[(isB ? BB : 0) + p * 512 + fi * 64]);
        }
        __syncthreads();
        const bf16x8* ldsb = (const bf16x8*)lds;
        bf16x8 afr[4][NP];
        #pragma unroll
        for (int fm = 0; fm < 4; fm++)
            #pragma unroll
            for (int p = 0; p < NP; p++)
                afr[fm][p] = ldsb[p * 512 + (wm * 4 + fm) * 64 + lane];
        #pragma unroll
        for (int fn = 0; fn < 4; fn++) {
            bf16x8 b0 = ldsb[BB + 0 * 512 + (wn * 4 + fn) * 64 + lane];
            bf16x8 b1 = ldsb[BB + 1 * 512 + (wn * 4 + fn) * 64 + lane];
            bf16x8 b2;
            if constexpr (NP == 3) b2 = ldsb[BB + 2 * 512 + (wn * 4 + fn) * 64 + lane];
            #pragma unroll
            for (int fm = 0; fm < 4; fm++) {
                f32x4 t = acc[fm][fn];
                if constexpr (NP == 3) {
                    t = mfma_bf16(afr[fm][0], b0, t);
                    t = mfma_bf16(afr[fm][1], b0, t);
                    t = mfma_bf16(afr[fm][2], b0, t);
                    t = mfma_bf16(afr[fm][0], b1, t);
                    t = mfma_bf16(afr[fm][1], b1, t);
                    t = mfma_bf16(afr[fm][0], b2, t);
                } else {
                    t = mfma_bf16(afr[fm][0], b0, t);
                    t = mfma_bf16(afr[fm][1], b0, t);
                    t = mfma_bf16(afr[fm][0], b1, t);
                }
                acc[fm][fn] = t;
            }
        }
        __syncthreads();
    }
    #pragma unroll
    for (int fm = 0; fm < 4; fm++) {
        int row0 = m0 + (wm * 4 + fm) * 16 + (lane >> 4) * 4;
        #pragma unroll
        for (int fn = 0; fn < 4; fn++) {
            int col = n0 + (wn * 4 + fn) * 16 + (lane & 15);
            float bv = bias[col];
            f32x4 a = acc[fm][fn];
            #pragma unroll
            for (int r = 0; r < 4; r++) {
                int row = row0 + r;
                float val = a[r] + bv;
                if (RELU) val = fmaxf(val, 0.f);
                if constexpr (OUTP == 0) {
                    C[(size_t)row * ldc + col] = val;
                } else {
                    unsigned int h0 = bf16_rne(val);
                    float r1 = val - __uint_as_float(h0 << 16);
                    unsigned int h1 = bf16_rne(r1);
                    size_t o = (size_t)row * ldc + col;
                    Cpl[o] = (ushort_t)h0;
                    Cpl[Celems + o] = (ushort_t)h1;
                    if constexpr (NP == 3) {
                        float r2 = r1 - __uint_as_float(h1 << 16);
                        Cpl[2 * Celems + o] = (ushort_t)bf16_rne(r2);
                    }
                }
            }
        }
    }
}

// ---------------- unified split-6 bf16-MFMA matmul (fallback path only) ----------------
template <int MODE, int TN>
__global__ __launch_bounds__(256) void mm6(const float* __restrict__ Aall,
                                           const float* __restrict__ Ball,
                                           float* __restrict__ Call,
                                           const float* __restrict__ bias,
                                           int lda, int ldb, int ldc, int K) {
    constexpr int BFR = TN / 16;
    constexpr int MFR = (TN == 128) ? 4 : 2;
    constexpr int BBASE = 3 * 8 * 64;
    __shared__ uint4 lds[3 * 8 * 64 + 3 * BFR * 64];

    const int tid = threadIdx.x, lane = tid & 63, wid = tid >> 6;
    const int wm = (TN == 128) ? (wid >> 1) : wid;
    const int wn = (TN == 128) ? (wid & 1) : 0;

    const float* A;
    const float* B;
    float* C;
    int m0, n0, kmax;
    if constexpr (MODE <= 1) {
        m0 = blockIdx.y * 128;
        n0 = blockIdx.x * 128;
        A = Aall; B = Ball; C = Call;
        kmax = K;
    } else {
        const int bh = blockIdx.y, b = bh >> 3, h = bh & 7, rb = blockIdx.x;
        m0 = rb * 128; n0 = 0;
        A = Aall + (size_t)bh * SEQ * SEQ;
        B = Ball + (size_t)bh * DKH * SEQ;
        C = Call + ((size_t)b * SEQ) * DIM + h * DKH;
        kmax = rb ? (rb + 1) * 128 : SEQ;
    }

    f32x4 acc[MFR][4] = {};

    for (int k0 = 0; k0 < kmax; k0 += 32) {
        for (int c = tid; c < (8 + BFR) * 64; c += 256) {
            int fi = c >> 6, lc = c & 63;
            const float* src = (fi < 8)
                ? A + (size_t)(m0 + fi * 16 + (lc & 15)) * lda + k0 + (lc >> 4) * 8
                : B + (size_t)(n0 + (fi - 8) * 16 + (lc & 15)) * ldb + k0 + (lc >> 4) * 8;
            float4 x0 = *(const float4*)src;
            float4 x1 = *(const float4*)(src + 4);
            float xs[8] = {x0.x, x0.y, x0.z, x0.w, x1.x, x1.y, x1.z, x1.w};
            unsigned int hh[8], hm[8], hl[8];
            split3_8(xs, hh, hm, hl);
            int base = (fi < 8) ? fi * 64 + lc : BBASE + (fi - 8) * 64 + lc;
            int fstride = (fi < 8) ? 8 * 64 : BFR * 64;
            lds[base + 0 * fstride] = pack8(hh);
            lds[base + 1 * fstride] = pack8(hm);
            lds[base + 2 * fstride] = pack8(hl);
        }
        __syncthreads();

        const bf16x8* ldsb = (const bf16x8*)lds;
        bf16x8 afr[MFR][3];
        #pragma unroll
        for (int fm = 0; fm < MFR; fm++)
            #pragma unroll
            for (int p = 0; p < 3; p++)
                afr[fm][p] = ldsb[p * 512 + (wm * MFR + fm) * 64 + lane];
        #pragma unroll
        for (int fn = 0; fn < 4; fn++) {
            bf16x8 b0 = ldsb[BBASE + 0 * (BFR * 64) + (wn * 4 + fn) * 64 + lane];
            bf16x8 b1 = ldsb[BBASE + 1 * (BFR * 64) + (wn * 4 + fn) * 64 + lane];
            bf16x8 b2 = ldsb[BBASE + 2 * (BFR * 64) + (wn * 4 + fn) * 64 + lane];
            #pragma unroll
            for (int fm = 0; fm < MFR; fm++) {
                f32x4 t = acc[fm][fn];
                t = mfma_bf16(afr[fm][0], b0, t);
                t = mfma_bf16(afr[fm][1], b0, t);
                t = mfma_bf16(afr[fm][2], b0, t);
                t = mfma_bf16(afr[fm][0], b1, t);
                t = mfma_bf16(afr[fm][1], b1, t);
                t = mfma_bf16(afr[fm][0], b2, t);
                acc[fm][fn] = t;
            }
        }
        __syncthreads();
    }

    #pragma unroll
    for (int fm = 0; fm < MFR; fm++) {
        int row0 = m0 + (wm * MFR + fm) * 16 + (lane >> 4) * 4;
        #pragma unroll
        for (int fn = 0; fn < 4; fn++) {
            int col = n0 + (wn * 4 + fn) * 16 + (lane & 15);
            float bv = 0.f;
            if constexpr (MODE <= 1) bv = bias[col];
            f32x4 a = acc[fm][fn];
            #pragma unroll
            for (int r = 0; r < 4; r++) {
                int row = row0 + r;
                float val;
                if constexpr (MODE == 0) val = a[r] + bv;
                else if constexpr (MODE == 1) val = fmaxf(a[r] + bv, 0.f);
                else val = (row == 0) ? 0.f : a[r];
                C[(size_t)row * ldc + col] = val;
            }
        }
    }
}

// ---------------- AV with NP-plane output ----------------
template <int NP>
__global__ __launch_bounds__(256) void mm6av_pl(const float* __restrict__ pbuf,
                                                const float* __restrict__ vt,
                                                ushort_t* __restrict__ Opl, size_t Oelems) {
    constexpr int BBASE = NP * 512;
    __shared__ uint4 lds[NP * 512 + NP * 256];
    const int tid = threadIdx.x, lane = tid & 63, wid = tid >> 6;
    const int bh = blockIdx.y, b = bh >> 3, h = bh & 7, rb = blockIdx.x;
    const int m0 = rb * 128;
    const float* A = pbuf + (size_t)bh * SEQ * SEQ;
    const float* B = vt + (size_t)bh * DKH * SEQ;
    const int kmax = rb ? (rb + 1) * 128 : SEQ;

    f32x4 acc[2][4] = {};
    for (int k0 = 0; k0 < kmax; k0 += 32) {
        for (int c = tid; c < 12 * 64; c += 256) {
            int fi = c >> 6, lc = c & 63;
            const float* src = (fi < 8)
                ? A + (size_t)(m0 + fi * 16 + (lc & 15)) * SEQ + k0 + (lc >> 4) * 8
                : B + (size_t)((fi - 8) * 16 + (lc & 15)) * SEQ + k0 + (lc >> 4) * 8;
            float4 x0 = *(const float4*)src;
            float4 x1 = *(const float4*)(src + 4);
            float xs[8] = {x0.x, x0.y, x0.z, x0.w, x1.x, x1.y, x1.z, x1.w};
            unsigned int hh[8], hm[8], hl[8];
            split3_8(xs, hh, hm, hl);
            int base, fstride;
            if (fi < 8) { base = fi * 64 + lc; fstride = 512; }
            else { base = BBASE + (fi - 8) * 64 + lc; fstride = 256; }
            lds[base] = pack8(hh);
            lds[base + fstride] = pack8(hm);
            if (NP == 3) lds[base + 2 * fstride] = pack8(hl);
        }
        __syncthreads();
        const bf16x8* ldsb = (const bf16x8*)lds;
        bf16x8 afr[2][NP];
        #pragma unroll
        for (int fm = 0; fm < 2; fm++)
            #pragma unroll
            for (int p = 0; p < NP; p++)
                afr[fm][p] = ldsb[p * 512 + (wid * 2 + fm) * 64 + lane];
        #pragma unroll
        for (int fn = 0; fn < 4; fn++) {
            bf16x8 b0 = ldsb[BBASE + 0 * 256 + fn * 64 + lane];
            bf16x8 b1 = ldsb[BBASE + 1 * 256 + fn * 64 + lane];
            bf16x8 b2;
            if constexpr (NP == 3) b2 = ldsb[BBASE + 2 * 256 + fn * 64 + lane];
            #pragma unroll
            for (int fm = 0; fm < 2; fm++) {
                f32x4 t = acc[fm][fn];
                if constexpr (NP == 3) {
                    t = mfma_bf16(afr[fm][0], b0, t);
                    t = mfma_bf16(afr[fm][1], b0, t);
                    t = mfma_bf16(afr[fm][2], b0, t);
                    t = mfma_bf16(afr[fm][0], b1, t);
                    t = mfma_bf16(afr[fm][1], b1, t);
                    t = mfma_bf16(afr[fm][0], b2, t);
                } else {
                    t = mfma_bf16(afr[fm][0], b0, t);
                    t = mfma_bf16(afr[fm][1], b0, t);
                    t = mfma_bf16(afr[fm][0], b1, t);
                }
                acc[fm][fn] = t;
            }
        }
        __syncthreads();
    }
    #pragma unroll
    for (int fm = 0; fm < 2; fm++) {
        int row0 = m0 + (wid * 2 + fm) * 16 + (lane >> 4) * 4;
        #pragma unroll
        for (int fn = 0; fn < 4; fn++) {
            int col = fn * 16 + (lane & 15);
            f32x4 a = acc[fm][fn];
            #pragma unroll
            for (int r = 0; r < 4; r++) {
                int row = row0 + r;
                float val = (row == 0) ? 0.f : a[r];
                unsigned int h0 = bf16_rne(val);
                float r1 = val - __uint_as_float(h0 << 16);
                unsigned int h1 = bf16_rne(r1);
                size_t o = ((size_t)b * SEQ + row) * DIM + h * DKH + col;
                Opl[o] = (ushort_t)h0;
                Opl[Oelems + o] = (ushort_t)h1;
                if constexpr (NP == 3) {
                    float r2 = r1 - __uint_as_float(h1 << 16);
                    Opl[2 * Oelems + o] = (ushort_t)bf16_rne(r2);
                }
            }
        }
    }
}

// ---------------- V transpose ----------------
__global__ __launch_bounds__(256) void transpose_v_kernel(const float* __restrict__ v,
                                                          float* __restrict__ vt) {
    const int bh = blockIdx.y, jt = blockIdx.x;
    const int b = bh >> 3, h = bh & 7;
    __shared__ float L[64][65];
    const int tid = threadIdx.x;
    for (int s = tid; s < 1024; s += 256) {
        int jj = s >> 4, d4 = s & 15;
        float4 x = *(const float4*)(v + ((size_t)(b * SEQ) + jt * 64 + jj) * DIM + h * DKH + d4 * 4);
        L[jj][d4 * 4 + 0] = x.x; L[jj][d4 * 4 + 1] = x.y;
        L[jj][d4 * 4 + 2] = x.z; L[jj][d4 * 4 + 3] = x.w;
    }
    __syncthreads();
    int d = tid >> 2, jq = tid & 3;
    float* dst = vt + ((size_t)bh * DKH + d) * SEQ + jt * 64 + jq * 16;
    #pragma unroll
    for (int c4 = 0; c4 < 4; c4++) {
        float4 o = make_float4(L[jq * 16 + c4 * 4 + 0][d], L[jq * 16 + c4 * 4 + 1][d],
                               L[jq * 16 + c4 * 4 + 2][d], L[jq * 16 + c4 * 4 + 3][d]);
        *(float4*)(dst + c4 * 4) = o;
    }
}

// ---------------- softmax -> top5 -> second softmax ----------------
__global__ __launch_bounds__(64)
void softmax_topk_kernel(float* __restrict__ pbuf) {
    const int i = blockIdx.x;
    const size_t row = (size_t)blockIdx.y * SEQ + i;
    const int lane = threadIdx.x;
    float* p = pbuf + row * SEQ;
    float v[8];
    {
        int j0 = lane * 4;
        if (j0 < i) {
            float4 x0 = *(const float4*)(p + j0);
            v[0] = (j0 + 0 < i) ? x0.x : NEGV;
            v[1] = (j0 + 1 < i) ? x0.y : NEGV;
            v[2] = (j0 + 2 < i) ? x0.z : NEGV;
            v[3] = (j0 + 3 < i) ? x0.w : NEGV;
        } else { v[0] = v[1] = v[2] = v[3] = NEGV; }
        int j1 = 256 + j0;
        if (j1 < i) {
            float4 x1 = *(const float4*)(p + j1);
            v[4] = (j1 + 0 < i) ? x1.x : NEGV;
            v[5] = (j1 + 1 < i) ? x1.y : NEGV;
            v[6] = (j1 + 2 < i) ? x1.z : NEGV;
            v[7] = (j1 + 3 < i) ? x1.w : NEGV;
        } else { v[4] = v[5] = v[6] = v[7] = NEGV; }
    }
    float lm = v[0];
    #pragma unroll
    for (int e = 1; e < 8; e++) lm = fmaxf(lm, v[e]);
    float m1 = wmaxf(lm);
    float ls = 0.f;
    #pragma unroll
    for (int e = 0; e < 8; e++) { v[e] = expf(v[e] - m1); ls += v[e]; }
    float Z = wsumf(ls);
    #pragma unroll
    for (int e = 0; e < 8; e++) v[e] = v[e] / Z;
    float thr = -INFINITY;
    if (i >= KIDX) {
        int remaining = KIDX;
        float cut = INFINITY;
        #pragma unroll 1
        for (int iter = 0; iter < KIDX; iter++) {
            float l2 = -INFINITY;
            #pragma unroll
            for (int e = 0; e < 8; e++) if (v[e] < cut) l2 = fmaxf(l2, v[e]);
            float m2 = wmaxf(l2);
            int lc = 0;
            #pragma unroll
            for (int e = 0; e < 8; e++) if (v[e] == m2) lc++;
            int c = wsumi(lc);
            if (c >= remaining) { thr = m2; break; }
            remaining -= c; cut = m2;
        }
    }
    float lpm = v[0];
    #pragma unroll
    for (int e = 1; e < 8; e++) lpm = fmaxf(lpm, v[e]);
    float pm = wmaxf(lpm);
    float t[8];
    float ls2 = 0.f;
    #pragma unroll
    for (int e = 0; e < 8; e++) {
        bool keep = (i >= KIDX) ? (v[e] >= thr) : true;
        t[e] = keep ? expf(v[e] - pm) : 0.f;
        ls2 += t[e];
    }
    float Z2 = wsumf(ls2);
    #pragma unroll
    for (int e = 0; e < 8; e++) t[e] = t[e] / Z2;
    *(float4*)(p + lane * 4) = make_float4(t[0], t[1], t[2], t[3]);
    *(float4*)(p + 256 + lane * 4) = make_float4(t[4], t[5], t[6], t[7]);
}

// ---------------- dst = LN(x + t)  (EMIT: also write 3 bf16 planes of dst) ----------------
template <int EMIT>
__global__ __launch_bounds__(64)
void add_ln_kernel(const float* __restrict__ x, const float* __restrict__ t,
                   const float* __restrict__ w, const float* __restrict__ b,
                   float* __restrict__ dst, ushort_t* __restrict__ dpl, size_t delems) {
    const size_t row = blockIdx.x;
    const int lane = threadIdx.x;
    const float* xr = x + row * DIM;
    const float* tr = t + row * DIM;
    float v[8];
    {
        float4 a0 = *(const float4*)(xr + lane * 4);
        float4 t0 = *(const float4*)(tr + lane * 4);
        float4 a1 = *(const float4*)(xr + 256 + lane * 4);
        float4 t1 = *(const float4*)(tr + 256 + lane * 4);
        v[0] = a0.x + t0.x; v[1] = a0.y + t0.y; v[2] = a0.z + t0.z; v[3] = a0.w + t0.w;
        v[4] = a1.x + t1.x; v[5] = a1.y + t1.y; v[6] = a1.z + t1.z; v[7] = a1.w + t1.w;
    }
    float ls = 0.f;
    #pragma unroll
    for (int e = 0; e < 8; e++) ls += v[e];
    float mean = wsumf(ls) / (float)DIM;
    float ld = 0.f;
    #pragma unroll
    for (int e = 0; e < 8; e++) { float d = v[e] - mean; ld += d * d; }
    float var = wsumf(ld) / (float)DIM;
    float den = sqrtf(var + 1e-5f);
    float wv[8], bv[8];
    *(float4*)&wv[0] = *(const float4*)(w + lane * 4);
    *(float4*)&wv[4] = *(const float4*)(w + 256 + lane * 4);
    *(float4*)&bv[0] = *(const float4*)(b + lane * 4);
    *(float4*)&bv[4] = *(const float4*)(b + 256 + lane * 4);
    float o[8];
    #pragma unroll
    for (int e = 0; e < 8; e++) o[e] = (v[e] - mean) / den * wv[e] + bv[e];
    float* dr = dst + row * DIM;
    *(float4*)(dr + lane * 4) = make_float4(o[0], o[1], o[2], o[3]);
    *(float4*)(dr + 256 + lane * 4) = make_float4(o[4], o[5], o[6], o[7]);
    if constexpr (EMIT) {
        unsigned int hh[8], hm[8], hl[8];
        split3_8(o, hh, hm, hl);
        size_t base0 = row * DIM + lane * 4;
        size_t base1 = base0 + 256;
        #pragma unroll
        for (int p = 0; p < 3; p++) {
            const unsigned int* hp = (p == 0) ? hh : (p == 1) ? hm : hl;
            *(uint2*)(dpl + p * delems + base0) =
                make_uint2(hp[0] | (hp[1] << 16), hp[2] | (hp[3] << 16));
            *(uint2*)(dpl + p * delems + base1) =
                make_uint2(hp[4] | (hp[5] << 16), hp[6] | (hp[7] << 16));
        }
    }
}

extern "C" void kernel_launch(void* const* d_in, const int* in_sizes, int n_in,
                              void* d_out, int out_size, void* d_ws, size_t ws_size,
                              hipStream_t stream) {
    const float* q_embed = (const float*)d_in[0];
    const float* qa_embed = (const float*)d_in[1];
    const float* pe = (const float*)d_in[2];
    const float* Wk = (const float*)d_in[3];
    const float* bk = (const float*)d_in[4];
    const float* Wv = (const float*)d_in[5];
    const float* bv = (const float*)d_in[6];
    const float* Wo = (const float*)d_in[7];
    const float* bo = (const float*)d_in[8];
    const float* W1 = (const float*)d_in[9];
    const float* b1 = (const float*)d_in[10];
    const float* W2 = (const float*)d_in[11];
    const float* b2 = (const float*)d_in[12];
    const float* ln1w = (const float*)d_in[13];
    const float* ln1b = (const float*)d_in[14];
    const float* ln2w = (const float*)d_in[15];
    const float* ln2b = (const float*)d_in[16];

    float* outx = (float*)d_out;
    const size_t NE = (size_t)BSZ * SEQ * DIM;   // 8388608
    float* pbuf = outx + NE;
    float* ws = (float*)d_ws;
    const int M = BSZ * SEQ;

    const size_t need_new = 13 * NE * sizeof(float);  // ~436 MB
    if (ws_size >= need_new) {
        // ===================== NEW PATH: pre-split planes =====================
        float* xbuf = ws;
        float* qbuf = ws + NE;
        float* vbuf = ws + 2 * NE;
        ushort_t* y_pl = (ushort_t*)(ws + 3 * NE);
        ushort_t* x_pl = (ushort_t*)(ws + 4 * NE + NE / 2);
        ushort_t* w_pl = (ushort_t*)(ws + 6 * NE);
        float* vt = ws + 7 * NE;
        ushort_t* o_pl = (ushort_t*)(ws + 8 * NE);
        ushort_t* h1_pl = (ushort_t*)(ws + 7 * NE);

        const size_t WVE = (size_t)DIM * DIM;      // 262144
        const size_t W1E = (size_t)DFFN * DIM;     // 1048576
        const size_t LW = 3 * (WVE + WVE + W1E + W1E);

        for (int l = 0; l < NL; l++) {
            ushort_t* base = w_pl + (size_t)l * LW;
            split3w<<<(int)(WVE / 8 + 255) / 256, 256, 0, stream>>>(
                Wv + (size_t)l * WVE, base, WVE, (int)(WVE / 8));
            split3w<<<(int)(WVE / 8 + 255) / 256, 256, 0, stream>>>(
                Wo + (size_t)l * WVE, base + 3 * WVE, WVE, (int)(WVE / 8));
            split3w<<<(int)(W1E / 8 + 255) / 256, 256, 0, stream>>>(
                W1 + (size_t)l * W1E, base + 6 * WVE, W1E, (int)(W1E / 8));
            split3w<<<(int)(W1E / 8 + 255) / 256, 256, 0, stream>>>(
                W2 + (size_t)l * W1E, base + 6 * WVE + 3 * W1E, W1E, (int)(W1E / 8));
        }

        add_pe_new<<<(int)(NE / 8 + 255) / 256, 256, 0, stream>>>(
            q_embed, qa_embed, pe, xbuf, y_pl, NE, (int)(NE / 8));

        for (int l = 0; l < NL; l++) {
            ushort_t* wb = w_pl + (size_t)l * LW;
            ushort_t* Wv_pl = wb;
            ushort_t* Wo_pl = wb + 3 * WVE;
            ushort_t* W1_pl = wb + 6 * WVE;
            ushort_t* W2_pl = wb + 6 * WVE + 3 * W1E;

            // q = x @ Wk^T + bk  (fp32 exact — selection-critical)
            gemm_bt<0><<<dim3(DIM / 128, M / 128), 256, 0, stream>>>(
                xbuf, Wk + (size_t)l * WVE, bk + (size_t)l * DIM, qbuf, M, DIM, DIM);
            if (l == 0) {
                gemm3p<0, 0, 3><<<dim3(DIM / 128, M / 128), 256, 0, stream>>>(
                    y_pl, NE, DIM, Wv_pl, WVE, DIM, bv + (size_t)l * DIM,
                    vbuf, nullptr, 0, DIM, DIM);
            } else {
                gemm3p<0, 0, 2><<<dim3(DIM / 128, M / 128), 256, 0, stream>>>(
                    y_pl, NE, DIM, Wv_pl, WVE, DIM, bv + (size_t)l * DIM,
                    vbuf, nullptr, 0, DIM, DIM);
            }
            transpose_v_kernel<<<dim3(8, BSZ * NH), 256, 0, stream>>>(vbuf, vt);
            scores128_kernel<<<dim3(10, BSZ * NH), 256, 0, stream>>>(qbuf, pbuf);
            softmax_topk_kernel<<<dim3(SEQ, BSZ * NH), 64, 0, stream>>>(pbuf);
            if (l == 0) {
                mm6av_pl<3><<<dim3(4, BSZ * NH), 256, 0, stream>>>(pbuf, vt, o_pl, NE);
                gemm3p<0, 0, 3><<<dim3(DIM / 128, M / 128), 256, 0, stream>>>(
                    o_pl, NE, DIM, Wo_pl, WVE, DIM, bo + (size_t)l * DIM,
                    qbuf, nullptr, 0, DIM, DIM);
            } else {
                mm6av_pl<2><<<dim3(4, BSZ * NH), 256, 0, stream>>>(pbuf, vt, o_pl, NE);
                gemm3p<0, 0, 2><<<dim3(DIM / 128, M / 128), 256, 0, stream>>>(
                    o_pl, NE, DIM, Wo_pl, WVE, DIM, bo + (size_t)l * DIM,
                    qbuf, nullptr, 0, DIM, DIM);
            }
            add_ln_kernel<1><<<M, 64, 0, stream>>>(
                xbuf, qbuf, ln1w + (size_t)l * DIM, ln1b + (size_t)l * DIM,
                xbuf, x_pl, NE);
            if (l == 0) {
                gemm3p<1, 1, 3><<<dim3(DFFN / 128, M / 128), 256, 0, stream>>>(
                    x_pl, NE, DIM, W1_pl, W1E, DIM, b1 + (size_t)l * DFFN,
                    nullptr, h1_pl, (size_t)M * DFFN, DFFN, DIM);
                gemm3p<0, 0, 3><<<dim3(DIM / 128, M / 128), 256, 0, stream>>>(
                    h1_pl, (size_t)M * DFFN, DFFN, W2_pl, W1E, DFFN, b2 + (size_t)l * DIM,
                    vbuf, nullptr, 0, DIM, DFFN);
            } else {
                gemm3p<1, 1, 2><<<dim3(DFFN / 128, M / 128), 256, 0, stream>>>(
                    x_pl, NE, DIM, W1_pl, W1E, DIM, b1 + (size_t)l * DFFN,
                    nullptr, h1_pl, (size_t)M * DFFN, DFFN, DIM);
                gemm3p<0, 0, 2><<<dim3(DIM / 128, M / 128), 256, 0, stream>>>(
                    h1_pl, (size_t)M * DFFN, DFFN, W2_pl, W1E, DFFN, b2 + (size_t)l * DIM,
                    vbuf, nullptr, 0, DIM, DFFN);
            }
            float* dst = (l == NL - 1) ? outx : xbuf;
            add_ln_kernel<0><<<M, 64, 0, stream>>>(
                xbuf, vbuf, ln2w + (size_t)l * DIM, ln2b + (size_t)l * DIM,
                dst, nullptr, 0);
        }
    } else {
        // ===================== FALLBACK: round-4 path =====================
        float* xbuf = ws;
        float* ybuf = ws + NE;
        float* qbuf = ws + 2 * NE;
        float* vbuf = ws + 3 * NE;
        float* obuf = ws + 4 * NE;
        float* vtbuf = ws + 5 * NE;
        float* h1buf = ws + 5 * NE;

        {
            int n4 = (int)(NE / 4);
            add_pe_old<<<(n4 + 255) / 256, 256, 0, stream>>>(
                (const float4*)q_embed, (const float4*)qa_embed, (const float4*)pe,
                (float4*)xbuf, (float4*)ybuf, n4);
        }
        for (int l = 0; l < NL; l++) {
            const float* Wk_l = Wk + (size_t)l * DIM * DIM;
            const float* Wv_l = Wv + (size_t)l * DIM * DIM;
            const float* Wo_l = Wo + (size_t)l * DIM * DIM;
            const float* W1_l = W1 + (size_t)l * DFFN * DIM;
            const float* W2_l = W2 + (size_t)l * DIM * DFFN;

            gemm_bt<0><<<dim3(DIM / 128, M / 128), 256, 0, stream>>>(
                xbuf, Wk_l, bk + (size_t)l * DIM, qbuf, M, DIM, DIM);
            mm6<0, 128><<<dim3(DIM / 128, M / 128), 256, 0, stream>>>(
                ybuf, Wv_l, vbuf, bv + (size_t)l * DIM, DIM, DIM, DIM, DIM);
            transpose_v_kernel<<<dim3(8, BSZ * NH), 256, 0, stream>>>(vbuf, vtbuf);
            scores128_kernel<<<dim3(10, BSZ * NH), 256, 0, stream>>>(qbuf, pbuf);
            softmax_topk_kernel<<<dim3(SEQ, BSZ * NH), 64, 0, stream>>>(pbuf);
            mm6<3, 64><<<dim3(4, BSZ * NH), 256, 0, stream>>>(
                pbuf, vtbuf, obuf, nullptr, SEQ, SEQ, DIM, SEQ);
            mm6<0, 128><<<dim3(DIM / 128, M / 128), 256, 0, stream>>>(
                obuf, Wo_l, qbuf, bo + (size_t)l * DIM, DIM, DIM, DIM, DIM);
            add_ln_kernel<0><<<M, 64, 0, stream>>>(
                xbuf, qbuf, ln1w + (size_t)l * DIM, ln1b + (size_t)l * DIM,
                xbuf, nullptr, 0);
            mm6<1, 128><<<dim3(DFFN / 128, M / 128), 256, 0, stream>>>(
                xbuf, W1_l, h1buf, b1 + (size_t)l * DFFN, DIM, DIM, DFFN, DIM);
            mm6<0, 128><<<dim3(DIM / 128, M / 128), 256, 0, stream>>>(
                h1buf, W2_l, vbuf, b2 + (size_t)l * DIM, DFFN, DFFN, DIM, DFFN);
            float* dst = (l == NL - 1) ? outx : xbuf;
            add_ln_kernel<0><<<M, 64, 0, stream>>>(
                xbuf, vbuf, ln2w + (size_t)l * DIM, ln2b + (size_t)l * DIM,
                dst, nullptr, 0);
        }
    }
}